// Round 5
// baseline (13613.855 us; speedup 1.0000x reference)
//
#include <hip/hip_runtime.h>
#include <hip/hip_bf16.h>

// ---------------- problem constants ----------------
#define LDIM   1851   // L = TT - TINI - NH + 1
#define NFR    1000   // rows of F = [Uf(400); Yf(600)]
#define NAR    506    // rows of A = [Up(200); Yp(300); Yf_last(6)]
#define NCRP   1536   // padded rows of C = [F; A]
#define LDC    1856   // padded Hankel width
#define NG     1024   // padded G dim
#define NS     512    // padded S dim
#define NXC    1152   // padded X12 cols (1106 -> 1152)
#define LDMA   1120   // padded M_all cols (1100 -> 1120)
#define NBATCH 4096
#define NOUT   1000
#define INVDP  500000.0   // 1/(2*DELTA)
#define NBLK   240        // coop-style grid: <= 256 CUs -> all blocks resident

// ---------------- ws layout (bytes), lifetime-overlaid, total ~77.3 MB ----------------
#define OFF_C     ((size_t)0)
#define SZ_C      ((size_t)NCRP * LDC * 4)            // C dead after k_gram
#define OFF_ILG   OFF_C                               // 1024*1024*8 (over C)
#define OFF_ILS   (OFF_C + 8388608)                   // 512*512*8 (over C)
#define OFF_BAR   (OFF_C + 10485760)                  // 64B barrier counter (C hole, after ILS)
#define OFF_GCC   (OFF_C + SZ_C)
#define SZ_GCC    ((size_t)NCRP * NCRP * 8)
#define OFF_G     (OFF_GCC + SZ_GCC)
#define SZ_G      ((size_t)NG * NG * 8)
#define OFF_TA    (OFF_G + SZ_G)
#define SZ_TA     ((size_t)NG * NS * 8)
#define OFF_S     (OFF_TA + SZ_TA)
#define SZ_S      ((size_t)NS * NS * 8)
#define OFF_X12   (OFF_S + SZ_S)
#define SZ_X12    ((size_t)NS * NXC * 8)
#define OFF_MRAW  (OFF_X12 + SZ_X12)
#define SZ_MRAW   ((size_t)NG * NXC * 4)
#define OFF_XB    OFF_MRAW                            // XB dead before MRAW written
#define OFF_MALL  (OFF_MRAW + SZ_MRAW)
#define SZ_MALL   ((size_t)NG * LDMA * 4)             // written at very end of coop
#define OFF_IDG   OFF_MALL                            // 16*4096*8
#define OFF_IDS   (OFF_MALL + 524288)                 // 8*4096*8
#define OFF_WG    (OFF_MALL + 786432)                 // 16*4096*8
#define OFF_WS    (OFF_MALL + 1310720)                // 8*4096*8
#define OFF_LS    (OFF_MALL + 1572864)                // 512*512*8 (ends 3.67MB < 4.59MB)
#define OFF_INALL (OFF_MALL + SZ_MALL)
#define SZ_INALL  ((size_t)LDMA * NBATCH * 4)         // written late by transpose
#define OFF_TB    OFF_INALL                           // 1024*512*8
#define OFF_TINV  (OFF_INALL + 4194304)               // 512*512*8
#define OFF_LG    (OFF_INALL + 6291456)               // 1024*1024*8 (ends 14.68MB < 18.35MB)

__device__ __forceinline__ double dweight(int i, const float* q, const float* r) {
  return (i < 400) ? (double)r[i] : (double)q[i - 400];
}

// ==================== software grid barrier (all 240 blocks resident) ====================
// Monotonic-phase barrier: every block executes the SAME sequence of gbar() calls.
// Counter zeroed via hipMemsetAsync before the kernel; agent-scope atomics + fences
// per guide G12/G16 (device-scope coherent across XCDs).
__device__ __forceinline__ void gbar(unsigned int* cnt, unsigned int* phase) {
  __syncthreads();
  __threadfence();
  if (threadIdx.x == 0) {
    unsigned int target = (++(*phase)) * (unsigned int)gridDim.x;
    __hip_atomic_fetch_add(cnt, 1u, __ATOMIC_RELEASE, __HIP_MEMORY_SCOPE_AGENT);
    while (__hip_atomic_load(cnt, __ATOMIC_ACQUIRE, __HIP_MEMORY_SCOPE_AGENT) < target) {
      __builtin_amdgcn_s_sleep(2);
    }
  }
  __threadfence();
  __syncthreads();
}

// ==================== standalone kernels ====================

__global__ __launch_bounds__(256) void k_build_C(const float* __restrict__ ud,
                                                 const float* __restrict__ yd,
                                                 float* __restrict__ C) {
  int j = blockIdx.x * 256 + threadIdx.x;
  int rr = blockIdx.y;
  if (j >= LDC) return;
  float v = 0.f;
  if (j < LDIM) {
    if (rr < 400)        v = ud[200 + rr + 4 * j];            // Uf
    else if (rr < 1000)  v = yd[300 + (rr - 400) + 6 * j];    // Yf
    else if (rr < 1200)  v = ud[(rr - 1000) + 4 * j];         // Up
    else if (rr < 1500)  v = yd[(rr - 1200) + 6 * j];         // Yp
    else if (rr < 1506)  v = yd[894 + (rr - 1500) + 6 * j];   // Yf[-P:]
  }
  C[(size_t)rr * LDC + j] = v;
}

// GCC = C * C^T, fp64 accumulation (64x64 lower tiles + mirror) — R2-proven version
__global__ __launch_bounds__(256) void k_gram(const float* __restrict__ C,
                                              double* __restrict__ GCC) {
  int ti = blockIdx.y, tj = blockIdx.x;
  if (ti < tj) return;
  __shared__ float As[64][33];
  __shared__ float Bs[64][33];
  int tid = threadIdx.x;
  int tr4 = (tid >> 4) * 4, tc4 = (tid & 15) * 4;
  double acc[4][4] = {};
  int i0 = ti * 64, j0 = tj * 64;
  for (int k0 = 0; k0 < LDC; k0 += 32) {
#pragma unroll
    for (int l = 0; l < 8; ++l) {
      int t = tid + l * 256;
      int rr = t >> 5, cc = t & 31;
      As[rr][cc] = C[(size_t)(i0 + rr) * LDC + k0 + cc];
      Bs[rr][cc] = C[(size_t)(j0 + rr) * LDC + k0 + cc];
    }
    __syncthreads();
#pragma unroll
    for (int kk = 0; kk < 32; ++kk) {
      double a[4], b[4];
#pragma unroll
      for (int i = 0; i < 4; ++i) a[i] = (double)As[tr4 + i][kk];
#pragma unroll
      for (int jx = 0; jx < 4; ++jx) b[jx] = (double)Bs[tc4 + jx][kk];
#pragma unroll
      for (int i = 0; i < 4; ++i)
#pragma unroll
        for (int jx = 0; jx < 4; ++jx) acc[i][jx] += a[i] * b[jx];
    }
    __syncthreads();
  }
#pragma unroll
  for (int i = 0; i < 4; ++i)
#pragma unroll
    for (int jx = 0; jx < 4; ++jx) {
      int gi = i0 + tr4 + i, gj = j0 + tc4 + jx;
      GCC[(size_t)gi * NCRP + gj] = acc[i][jx];
      if (ti != tj) GCC[(size_t)gj * NCRP + gi] = acc[i][jx];
    }
}

__global__ __launch_bounds__(256) void k_transpose_in(const float* __restrict__ ref,
                                                      const float* __restrict__ ui,
                                                      const float* __restrict__ yi,
                                                      float* __restrict__ INall) {
  __shared__ float t[32][33];
  int tx = threadIdx.x & 31, ty = threadIdx.x >> 5;  // 32 x 8
  int n0 = blockIdx.x * 32, j0 = blockIdx.y * 32;
#pragma unroll
  for (int p = 0; p < 4; ++p) {
    int nb = n0 + ty + p * 8;
    int j = j0 + tx;
    float v = 0.f;
    if (j < 600)        v = ref[(size_t)nb * 600 + j];
    else if (j < 800)   v = ui[(size_t)nb * 200 + (j - 600)];
    else if (j < 1100)  v = yi[(size_t)nb * 300 + (j - 800)];
    t[ty + p * 8][tx] = v;
  }
  __syncthreads();
#pragma unroll
  for (int p = 0; p < 4; ++p) {
    INall[(size_t)(j0 + ty + p * 8) * NBATCH + n0 + tx] = t[tx][ty + p * 8];
  }
}

__global__ __launch_bounds__(256) void k_gemm_out(const float* __restrict__ Mall,
                                                  const float* __restrict__ INall,
                                                  float* __restrict__ out) {
  __shared__ float As[32][132];
  __shared__ float Bs[32][132];
  int tid = threadIdx.x;
  int tr = tid >> 4, tc = tid & 15;
  int m0 = blockIdx.y * 128, n0 = blockIdx.x * 128;
  float acc[8][8] = {};
  for (int k0 = 0; k0 < LDMA; k0 += 32) {
#pragma unroll
    for (int l = 0; l < 16; ++l) {
      int t = tid + l * 256;
      int rr = t >> 5, cc = t & 31;
      As[cc][rr] = Mall[(size_t)(m0 + rr) * LDMA + k0 + cc];
    }
#pragma unroll
    for (int l = 0; l < 16; ++l) {
      int t = tid + l * 256;
      int rr = t >> 7, cc = t & 127;
      Bs[rr][cc] = INall[(size_t)(k0 + rr) * NBATCH + n0 + cc];
    }
    __syncthreads();
#pragma unroll
    for (int kk = 0; kk < 32; ++kk) {
      float4 a0 = *(const float4*)&As[kk][tr * 4];
      float4 a1 = *(const float4*)&As[kk][64 + tr * 4];
      float4 b0 = *(const float4*)&Bs[kk][tc * 4];
      float4 b1 = *(const float4*)&Bs[kk][64 + tc * 4];
      float av[8] = {a0.x, a0.y, a0.z, a0.w, a1.x, a1.y, a1.z, a1.w};
      float bv[8] = {b0.x, b0.y, b0.z, b0.w, b1.x, b1.y, b1.z, b1.w};
#pragma unroll
      for (int i = 0; i < 8; ++i)
#pragma unroll
        for (int jx = 0; jx < 8; ++jx) acc[i][jx] += av[i] * bv[jx];
    }
    __syncthreads();
  }
#pragma unroll
  for (int ih = 0; ih < 2; ++ih)
#pragma unroll
    for (int i = 0; i < 4; ++i) {
      int o = m0 + ih * 64 + tr * 4 + i;
      if (o < NOUT) {
#pragma unroll
        for (int jh = 0; jh < 2; ++jh) {
          float4 v = make_float4(acc[ih * 4 + i][jh * 4 + 0], acc[ih * 4 + i][jh * 4 + 1],
                                 acc[ih * 4 + i][jh * 4 + 2], acc[ih * 4 + i][jh * 4 + 3]);
          *(float4*)&out[(size_t)o * NBATCH + n0 + jh * 64 + tc * 4] = v;
        }
      }
    }
}

// ==================== device cores (shared pool: 6400 doubles = 51.2 KB) ====================

// R2-proven: factor 64x64 tile resident in sm (stride 65, pre-loaded + synced);
// invd[] at sm+4160. Writes L tile to Ldst (upper junk, never read), inv(L) to
// iLout (zeros above diag), W = iL^T iL to Wout.
__device__ __forceinline__ void potrf_inv_w(double* sm, int tid,
                                            double* Ldst, int ld,
                                            double* iLout, double* Wout) {
  double* invd = sm + 4160;
  for (int c = 0; c < 64; ++c) {
    if (tid == 0) sm[c * 65 + c] = sqrt(sm[c * 65 + c]);
    __syncthreads();
    double piv = sm[c * 65 + c];
    for (int rr = c + 1 + tid; rr < 64; rr += 256) sm[rr * 65 + c] /= piv;
    __syncthreads();
    for (int t = tid; t < 64 * 64; t += 256) {
      int rr = t >> 6, jj = t & 63;
      if (rr > c && jj > c) sm[rr * 65 + jj] -= sm[rr * 65 + c] * sm[jj * 65 + c];
    }
    __syncthreads();
  }
#pragma unroll
  for (int l = 0; l < 16; ++l) {
    int t = tid + l * 256;
    Ldst[(size_t)(t >> 6) * ld + (t & 63)] = sm[(t >> 6) * 65 + (t & 63)];
  }
  __syncthreads();
  if (tid < 64) invd[tid] = 1.0 / sm[tid * 65 + tid];
  __syncthreads();
  if (tid < 64) {            // thread c solves column c of inv(L) into upper of sm
    int c = tid;
    for (int r = c + 1; r < 64; ++r) {
      double s = sm[r * 65 + c] * invd[c];
      for (int j = c + 1; j < r; ++j) s += sm[r * 65 + j] * sm[c * 65 + j];
      sm[c * 65 + r] = -s * invd[r];
    }
  }
  __syncthreads();
#pragma unroll
  for (int l = 0; l < 16; ++l) {
    int t = tid + l * 256;
    int r = t >> 6, c = t & 63;
    iLout[t] = (r < c) ? 0.0 : (r == c ? invd[r] : sm[c * 65 + r]);
  }
  for (int idx = tid; idx < 4096; idx += 256) {   // W = iL^T iL
    int r = idx >> 6, c = idx & 63;
    int k2 = r > c ? r : c;
    double s = 0.0;
    for (; k2 < 64; ++k2) {
      double ar = (k2 == r) ? invd[r] : sm[r * 65 + k2];
      double ac = (k2 == c) ? invd[c] : sm[c * 65 + k2];
      s += ar * ac;
    }
    Wout[idx] = s;
  }
}

// fused panel step (R3-run-proven structure): block t < nbp*(nbp+1)/2 handles
// trailing tile (i,j); j==0 blocks also emit the L21 panel tile; block 0 then
// factors the next diagonal tile in-kernel.
#define PFS1(r, c) sm[(r) * 65 + (c)]
#define PFS2(r, c) sm[4288 + (r) * 33 + (c)]
__device__ __forceinline__ void chol_panel(double* sm, double* M, int ld, int k, int nbp,
                                           const double* iLcur, const double* Wcur,
                                           double* LGm, double* iLnext, double* Wnext) {
  int tid = threadIdx.x;
  int t = blockIdx.x;
  int tiles = nbp * (nbp + 1) / 2;
  if (t >= tiles) return;
  int i = 0;
  while ((i + 1) * (i + 2) / 2 <= t) ++i;
  int j = t - i * (i + 1) / 2;
  int tr4 = (tid >> 4) * 4, tc4 = (tid & 15) * 4;
  int rowAi = k + 64 + i * 64, rowAj = k + 64 + j * 64;

  // Phase A (j==0): Li = Ai * iL^T  -> LG panel
  if (j == 0) {
#pragma unroll
    for (int l = 0; l < 16; ++l) { int t2 = tid + l * 256; PFS1(t2 >> 6, t2 & 63) = iLcur[t2]; }
    __syncthreads();
    double li[4][4] = {};
    for (int k0 = 0; k0 < 64; k0 += 32) {
#pragma unroll
      for (int l = 0; l < 8; ++l) {
        int t2 = tid + l * 256;
        PFS2(t2 >> 5, t2 & 31) = M[(size_t)(rowAi + (t2 >> 5)) * ld + k + k0 + (t2 & 31)];
      }
      __syncthreads();
#pragma unroll
      for (int mm = 0; mm < 32; ++mm) {
        double a[4], b[4];
#pragma unroll
        for (int i2 = 0; i2 < 4; ++i2) a[i2] = PFS2(tr4 + i2, mm);
#pragma unroll
        for (int j2 = 0; j2 < 4; ++j2) b[j2] = PFS1(tc4 + j2, k0 + mm);
#pragma unroll
        for (int i2 = 0; i2 < 4; ++i2)
#pragma unroll
          for (int j2 = 0; j2 < 4; ++j2) li[i2][j2] += a[i2] * b[j2];
      }
      __syncthreads();
    }
#pragma unroll
    for (int i2 = 0; i2 < 4; ++i2)
#pragma unroll
      for (int j2 = 0; j2 < 4; ++j2)
        LGm[(size_t)(rowAi + tr4 + i2) * ld + k + tc4 + j2] = li[i2][j2];
  }
  __syncthreads();

  // Phase B: tile (i,j) -= Ai * W * Aj^T
#pragma unroll
  for (int l = 0; l < 16; ++l) { int t2 = tid + l * 256; PFS1(t2 >> 6, t2 & 63) = Wcur[t2]; }
  __syncthreads();
  double acc[4][4] = {};
  for (int k0 = 0; k0 < 64; k0 += 32) {   // D1 = W * Aj^T
#pragma unroll
    for (int l = 0; l < 8; ++l) {
      int t2 = tid + l * 256;
      PFS2(t2 >> 5, t2 & 31) = M[(size_t)(rowAj + (t2 >> 5)) * ld + k + k0 + (t2 & 31)];
    }
    __syncthreads();
#pragma unroll
    for (int mm = 0; mm < 32; ++mm) {
      double a[4], b[4];
#pragma unroll
      for (int i2 = 0; i2 < 4; ++i2) a[i2] = PFS1(tr4 + i2, k0 + mm);
#pragma unroll
      for (int j2 = 0; j2 < 4; ++j2) b[j2] = PFS2(tc4 + j2, mm);
#pragma unroll
      for (int i2 = 0; i2 < 4; ++i2)
#pragma unroll
        for (int j2 = 0; j2 < 4; ++j2) acc[i2][j2] += a[i2] * b[j2];
    }
    __syncthreads();
  }
#pragma unroll
  for (int i2 = 0; i2 < 4; ++i2)   // stash D1 over dead W
#pragma unroll
    for (int j2 = 0; j2 < 4; ++j2) PFS1(tr4 + i2, tc4 + j2) = acc[i2][j2];
  __syncthreads();
  double acc2[4][4] = {};
  for (int k0 = 0; k0 < 64; k0 += 32) {   // C2 = Ai * D1
#pragma unroll
    for (int l = 0; l < 8; ++l) {
      int t2 = tid + l * 256;
      PFS2(t2 >> 5, t2 & 31) = M[(size_t)(rowAi + (t2 >> 5)) * ld + k + k0 + (t2 & 31)];
    }
    __syncthreads();
#pragma unroll
    for (int mm = 0; mm < 32; ++mm) {
      double a[4], b[4];
#pragma unroll
      for (int i2 = 0; i2 < 4; ++i2) a[i2] = PFS2(tr4 + i2, mm);
#pragma unroll
      for (int j2 = 0; j2 < 4; ++j2) b[j2] = PFS1(k0 + mm, tc4 + j2);
#pragma unroll
      for (int i2 = 0; i2 < 4; ++i2)
#pragma unroll
        for (int j2 = 0; j2 < 4; ++j2) acc2[i2][j2] += a[i2] * b[j2];
    }
    __syncthreads();
  }
  double upd[4][4];
#pragma unroll
  for (int i2 = 0; i2 < 4; ++i2)
#pragma unroll
    for (int j2 = 0; j2 < 4; ++j2) {
      size_t off = (size_t)(rowAi + tr4 + i2) * ld + rowAj + tc4 + j2;
      upd[i2][j2] = M[off] - acc2[i2][j2];
      M[off] = upd[i2][j2];
    }

  // Phase C (block 0 == tile (0,0) == next diagonal)
  if (t == 0) {
    __syncthreads();
#pragma unroll
    for (int i2 = 0; i2 < 4; ++i2)
#pragma unroll
      for (int j2 = 0; j2 < 4; ++j2) PFS1(tr4 + i2, tc4 + j2) = upd[i2][j2];
    __syncthreads();
    potrf_inv_w(sm, tid, LGm + (size_t)(k + 64) * ld + (k + 64), ld, iLnext, Wnext);
  }
}

// generic fp64 GEMM cores on the shared pool (64x64 C tile, 4x4 micro)
__device__ __forceinline__ void dgemm_nn_core(double* sm, const double* A, int lda,
                                              const double* B, int ldb,
                                              double* C, int ldc,
                                              int kBeg, int kEnd, double alpha) {
  double* As = sm;          // 64x33
  double* Bs = sm + 2112;   // 32x65
  int tid = threadIdx.x;
  int tr4 = (tid >> 4) * 4, tc4 = (tid & 15) * 4;
  double acc[4][4] = {};
  for (int k0 = kBeg; k0 < kEnd; k0 += 32) {
#pragma unroll
    for (int l = 0; l < 8; ++l) {
      int t = tid + l * 256;
      As[(t >> 5) * 33 + (t & 31)] = A[(size_t)(t >> 5) * lda + k0 + (t & 31)];
    }
#pragma unroll
    for (int l = 0; l < 8; ++l) {
      int t = tid + l * 256;
      Bs[(t >> 6) * 65 + (t & 63)] = B[(size_t)(k0 + (t >> 6)) * ldb + (t & 63)];
    }
    __syncthreads();
#pragma unroll
    for (int kk = 0; kk < 32; ++kk) {
      double a[4], b[4];
#pragma unroll
      for (int i = 0; i < 4; ++i) a[i] = As[(tr4 + i) * 33 + kk];
#pragma unroll
      for (int jx = 0; jx < 4; ++jx) b[jx] = Bs[kk * 65 + tc4 + jx];
#pragma unroll
      for (int i = 0; i < 4; ++i)
#pragma unroll
        for (int jx = 0; jx < 4; ++jx) acc[i][jx] += a[i] * b[jx];
    }
    __syncthreads();
  }
#pragma unroll
  for (int i = 0; i < 4; ++i)
#pragma unroll
    for (int jx = 0; jx < 4; ++jx)
      C[(size_t)(tr4 + i) * ldc + tc4 + jx] = alpha * acc[i][jx];
}

__device__ __forceinline__ void dgemm_tn_core(double* sm, const double* A, int lda,
                                              const double* B, int ldb,
                                              double* C, int ldc,
                                              int kBeg, int kEnd, double alpha) {
  double* Ls = sm;          // 32x65
  double* Bs = sm + 2080;   // 32x65
  int tid = threadIdx.x;
  int tr4 = (tid >> 4) * 4, tc4 = (tid & 15) * 4;
  double acc[4][4] = {};
  for (int k0 = kBeg; k0 < kEnd; k0 += 32) {
#pragma unroll
    for (int l = 0; l < 8; ++l) {
      int t = tid + l * 256;
      Ls[(t >> 6) * 65 + (t & 63)] = A[(size_t)(k0 + (t >> 6)) * lda + (t & 63)];
    }
#pragma unroll
    for (int l = 0; l < 8; ++l) {
      int t = tid + l * 256;
      Bs[(t >> 6) * 65 + (t & 63)] = B[(size_t)(k0 + (t >> 6)) * ldb + (t & 63)];
    }
    __syncthreads();
#pragma unroll
    for (int kk = 0; kk < 32; ++kk) {
      double a[4], b[4];
#pragma unroll
      for (int i = 0; i < 4; ++i) a[i] = Ls[kk * 65 + tr4 + i];
#pragma unroll
      for (int jx = 0; jx < 4; ++jx) b[jx] = Bs[kk * 65 + tc4 + jx];
#pragma unroll
      for (int i = 0; i < 4; ++i)
#pragma unroll
        for (int jx = 0; jx < 4; ++jx) acc[i][jx] += a[i] * b[jx];
    }
    __syncthreads();
  }
#pragma unroll
  for (int i = 0; i < 4; ++i)
#pragma unroll
    for (int jx = 0; jx < 4; ++jx)
      C[(size_t)(tr4 + i) * ldc + tc4 + jx] = alpha * acc[i][jx];
}

__device__ __forceinline__ void buildS_tile(double* sm, const double* GCC,
                                            const double* TA, double* S, int t) {
  double* Ga = sm;          // 64x33
  double* Tb = sm + 2112;   // 32x65
  int tid = threadIdx.x;
  int tr4 = (tid >> 4) * 4, tc4 = (tid & 15) * 4;
  int a0 = (t >> 3) * 64, b0 = (t & 7) * 64;
  double acc[4][4] = {};
  for (int f0 = 0; f0 < NG; f0 += 32) {
#pragma unroll
    for (int l = 0; l < 8; ++l) {
      int t2 = tid + l * 256;
      Ga[(t2 >> 5) * 33 + (t2 & 31)] = GCC[(size_t)(1000 + a0 + (t2 >> 5)) * NCRP + f0 + (t2 & 31)];
    }
#pragma unroll
    for (int l = 0; l < 8; ++l) {
      int t2 = tid + l * 256;
      Tb[(t2 >> 6) * 65 + (t2 & 63)] = TA[(size_t)(f0 + (t2 >> 6)) * NS + b0 + (t2 & 63)];
    }
    __syncthreads();
#pragma unroll
    for (int kk = 0; kk < 32; ++kk) {
      double a[4], b[4];
#pragma unroll
      for (int i = 0; i < 4; ++i) a[i] = Ga[(tr4 + i) * 33 + kk];
#pragma unroll
      for (int jx = 0; jx < 4; ++jx) b[jx] = Tb[kk * 65 + tc4 + jx];
#pragma unroll
      for (int i = 0; i < 4; ++i)
#pragma unroll
        for (int jx = 0; jx < 4; ++jx) acc[i][jx] += a[i] * b[jx];
    }
    __syncthreads();
  }
#pragma unroll
  for (int i = 0; i < 4; ++i)
#pragma unroll
    for (int jx = 0; jx < 4; ++jx) {
      int a = a0 + tr4 + i, b = b0 + tc4 + jx;
      double v;
      if (a < NAR && b < NAR)
        v = (GCC[(size_t)(1000 + a) * NCRP + 1000 + b] - acc[i][jx]) * INVDP;
      else
        v = (a == b) ? 1.0 : 0.0;
      S[(size_t)a * NS + b] = v;
    }
}

__device__ __forceinline__ void gemmM_tile(double* sm, const double* TA, const double* X12,
                                           const float* q, const float* r,
                                           float* Mraw, int t) {
  double* Ga = sm;          // 64x33
  double* Xb = sm + 2112;   // 32x65
  int tid = threadIdx.x;
  int tr4 = (tid >> 4) * 4, tc4 = (tid & 15) * 4;
  int o0 = (t / 18) * 64, c0 = (t % 18) * 64;
  double acc[4][4] = {};
  for (int k0 = 0; k0 < NS; k0 += 32) {
#pragma unroll
    for (int l = 0; l < 8; ++l) {
      int t2 = tid + l * 256;
      Ga[(t2 >> 5) * 33 + (t2 & 31)] = TA[(size_t)(o0 + (t2 >> 5)) * NS + k0 + (t2 & 31)];
    }
#pragma unroll
    for (int l = 0; l < 8; ++l) {
      int t2 = tid + l * 256;
      Xb[(t2 >> 6) * 65 + (t2 & 63)] = X12[(size_t)(k0 + (t2 >> 6)) * NXC + c0 + (t2 & 63)];
    }
    __syncthreads();
#pragma unroll
    for (int kk = 0; kk < 32; ++kk) {
      double a[4], b[4];
#pragma unroll
      for (int i = 0; i < 4; ++i) a[i] = Ga[(tr4 + i) * 33 + kk];
#pragma unroll
      for (int jx = 0; jx < 4; ++jx) b[jx] = Xb[kk * 65 + tc4 + jx];
#pragma unroll
      for (int i = 0; i < 4; ++i)
#pragma unroll
        for (int jx = 0; jx < 4; ++jx) acc[i][jx] += a[i] * b[jx];
    }
    __syncthreads();
  }
#pragma unroll
  for (int i = 0; i < 4; ++i)
#pragma unroll
    for (int jx = 0; jx < 4; ++jx) {
      int o = o0 + tr4 + i, col = c0 + tc4 + jx;
      float v = 0.f;
      if (o < NFR) {
        double scale = 1.0 / (2.0 * dweight(o, q, r));
        double tt = acc[i][jx] * scale;
        v = (float)((col < 600) ? -tt : tt);
      }
      Mraw[(size_t)o * NXC + col] = v;
    }
}

// ==================== the single-chain kernel (software grid barrier) ====================
__global__ __launch_bounds__(256) void k_coop(
    double* GCC, double* G, double* TA, double* S, double* X12,
    float* MRAW, float* MALL,
    double* ILG, double* ILS, double* IDG, double* IDS,
    double* WG, double* WS, double* LG, double* LS,
    double* TB, double* TINV, double* XB,
    const float* qv, const float* rv, unsigned int* bar) {
  __shared__ double sm[6400];  // 51.2 KB pool shared by all stage cores
  const int tid = threadIdx.x;
  const int bid = blockIdx.x;
  const int nbk = gridDim.x;
  const int gsz = nbk * 256;
  const int gix = bid * 256 + tid;
  unsigned int phase = 0;

  // ---- S1: G = GFF + (1e-6/d) I (identity-padded); TA = F A^T (zero-padded) ----
  for (int idx = gix; idx < NG * NG; idx += gsz) {
    int i = idx >> 10, j = idx & 1023;
    double v = (i < NFR && j < NFR) ? GCC[(size_t)i * NCRP + j] : 0.0;
    if (i == j) v = (i < NFR) ? v + 1e-6 / dweight(i, qv, rv) : 1.0;
    G[idx] = v;
  }
  for (int idx = gix; idx < NG * NS; idx += gsz) {
    int f = idx >> 9, a = idx & 511;
    TA[idx] = (f < NFR && a < NAR) ? GCC[(size_t)f * NCRP + 1000 + a] : 0.0;
  }
  gbar(bar, &phase);

  // ---- S2: Cholesky of G (16 panels) ----
  if (bid == 0) {
    for (int l = 0; l < 16; ++l) {
      int t2 = tid + l * 256;
      sm[(t2 >> 6) * 65 + (t2 & 63)] = G[(size_t)(t2 >> 6) * NG + (t2 & 63)];
    }
    __syncthreads();
    potrf_inv_w(sm, tid, LG, NG, IDG, WG);
  }
  gbar(bar, &phase);
  for (int p = 0; p < 15; ++p) {
    chol_panel(sm, G, NG, p * 64, 15 - p, IDG + (size_t)p * 4096, WG + (size_t)p * 4096,
               LG, IDG + (size_t)(p + 1) * 4096, WG + (size_t)(p + 1) * 4096);
    gbar(bar, &phase);
  }

  // ---- S3: iL_G via D&C (log depth) ----
  for (int idx = gix; idx < NG * NG; idx += gsz) {
    int i = idx >> 10, j = idx & 1023;
    int d = i >> 6;
    ILG[idx] = ((j >> 6) == d) ? IDG[(size_t)d * 4096 + (i & 63) * 64 + (j & 63)] : 0.0;
  }
  gbar(bar, &phase);
  for (int lv = 0; lv < 4; ++lv) {
    int half = 64 << lv, pairs = NG / (2 * half), hb = half >> 6;
    int tiles = pairs * hb * hb;
    for (int t = bid; t < tiles; t += nbk) {
      int p = t / (hb * hb), rem = t % (hb * hb), bi = rem / hb, bj = rem % hb;
      int base = p * 2 * half;
      dgemm_nn_core(sm, LG + (size_t)(base + half + bi * 64) * NG + base, NG,
                    ILG + (size_t)base * NG + base + bj * 64, NG,
                    TINV + (size_t)p * half * half + (size_t)bi * 64 * half + bj * 64, half,
                    0, half, 1.0);
    }
    gbar(bar, &phase);
    for (int t = bid; t < tiles; t += nbk) {
      int p = t / (hb * hb), rem = t % (hb * hb), bi = rem / hb, bj = rem % hb;
      int base = p * 2 * half;
      dgemm_nn_core(sm, ILG + (size_t)(base + half + bi * 64) * NG + base + half, NG,
                    TINV + (size_t)p * half * half + bj * 64, half,
                    ILG + (size_t)(base + half + bi * 64) * NG + base + bj * 64, NG,
                    0, half, -1.0);
    }
    gbar(bar, &phase);
  }

  // ---- S4: TA <- iL^T (iL TA)  (triangle-aware K ranges) ----
  for (int t = bid; t < 128; t += nbk) {
    int bi = t >> 3, bj = t & 7;
    dgemm_nn_core(sm, ILG + (size_t)bi * 64 * NG, NG, TA + bj * 64, NS,
                  TB + (size_t)bi * 64 * NS + bj * 64, NS, 0, (bi + 1) * 64, 1.0);
  }
  gbar(bar, &phase);
  for (int t = bid; t < 128; t += nbk) {
    int bi = t >> 3, bj = t & 7;
    dgemm_tn_core(sm, ILG + bi * 64, NG, TB + bj * 64, NS,
                  TA + (size_t)bi * 64 * NS + bj * 64, NS, bi * 64, NG, 1.0);
  }
  gbar(bar, &phase);

  // ---- S5: S = (GAA - GAF*TA)/(2*DELTA) ----
  for (int t = bid; t < 64; t += nbk) buildS_tile(sm, GCC, TA, S, t);
  gbar(bar, &phase);

  // ---- S6: Cholesky of S (8 panels) ----
  if (bid == 0) {
    for (int l = 0; l < 16; ++l) {
      int t2 = tid + l * 256;
      sm[(t2 >> 6) * 65 + (t2 & 63)] = S[(size_t)(t2 >> 6) * NS + (t2 & 63)];
    }
    __syncthreads();
    potrf_inv_w(sm, tid, LS, NS, IDS, WS);
  }
  gbar(bar, &phase);
  for (int p = 0; p < 7; ++p) {
    chol_panel(sm, S, NS, p * 64, 7 - p, IDS + (size_t)p * 4096, WS + (size_t)p * 4096,
               LS, IDS + (size_t)(p + 1) * 4096, WS + (size_t)(p + 1) * 4096);
    gbar(bar, &phase);
  }

  // ---- S7: iL_S via D&C ----
  for (int idx = gix; idx < NS * NS; idx += gsz) {
    int i = idx >> 9, j = idx & 511;
    int d = i >> 6;
    ILS[idx] = ((j >> 6) == d) ? IDS[(size_t)d * 4096 + (i & 63) * 64 + (j & 63)] : 0.0;
  }
  gbar(bar, &phase);
  for (int lv = 0; lv < 3; ++lv) {
    int half = 64 << lv, pairs = NS / (2 * half), hb = half >> 6;
    int tiles = pairs * hb * hb;
    for (int t = bid; t < tiles; t += nbk) {
      int p = t / (hb * hb), rem = t % (hb * hb), bi = rem / hb, bj = rem % hb;
      int base = p * 2 * half;
      dgemm_nn_core(sm, LS + (size_t)(base + half + bi * 64) * NS + base, NS,
                    ILS + (size_t)base * NS + base + bj * 64, NS,
                    TINV + (size_t)p * half * half + (size_t)bi * 64 * half + bj * 64, half,
                    0, half, 1.0);
    }
    gbar(bar, &phase);
    for (int t = bid; t < tiles; t += nbk) {
      int p = t / (hb * hb), rem = t % (hb * hb), bi = rem / hb, bj = rem % hb;
      int base = p * 2 * half;
      dgemm_nn_core(sm, ILS + (size_t)(base + half + bi * 64) * NS + base + half, NS,
                    TINV + (size_t)p * half * half + bj * 64, half,
                    ILS + (size_t)(base + half + bi * 64) * NS + base + bj * 64, NS,
                    0, half, -1.0);
    }
    gbar(bar, &phase);
  }

  // ---- S8: X12 = S^{-1} [TAq^T | I] ----
  for (int a = bid; a < NS; a += nbk)
    for (int c = tid; c < NXC; c += 256) {
      double v = 0.0;
      if (a < NAR) {
        if (c < 600) v = TA[(size_t)(400 + c) * NS + a];
        else if (c < 1106) v = (a == (c - 600)) ? 1.0 : 0.0;
      }
      X12[(size_t)a * NXC + c] = v;
    }
  gbar(bar, &phase);
  for (int t = bid; t < 8 * 18; t += nbk) {
    int bi = t / 18, bj = t % 18;
    dgemm_nn_core(sm, ILS + (size_t)bi * 64 * NS, NS, X12 + bj * 64, NXC,
                  XB + (size_t)bi * 64 * NXC + bj * 64, NXC, 0, (bi + 1) * 64, 1.0);
  }
  gbar(bar, &phase);
  for (int t = bid; t < 8 * 18; t += nbk) {
    int bi = t / 18, bj = t % 18;
    dgemm_tn_core(sm, ILS + bi * 64, NS, XB + bj * 64, NXC,
                  X12 + (size_t)bi * 64 * NXC + bj * 64, NXC, bi * 64, NS, 1.0);
  }
  gbar(bar, &phase);

  // ---- S9: Mraw ----
  for (int t = bid; t < 16 * 18; t += nbk) gemmM_tile(sm, TA, X12, qv, rv, MRAW, t);
  gbar(bar, &phase);

  // ---- S10: assemble fp32 map ----
  for (int o = bid; o < NG; o += nbk)
    for (int j2 = tid; j2 < LDMA; j2 += 256) {
      float v = 0.f;
      if (j2 < 600) {
        v = MRAW[(size_t)o * NXC + j2];
        if (o == 400 + j2) v += 1.0f;
        if (j2 >= 594) v += MRAW[(size_t)o * NXC + 1100 + (j2 - 594)];
      } else if (j2 < 1100) {
        v = MRAW[(size_t)o * NXC + j2];
      }
      MALL[(size_t)o * LDMA + j2] = v;
    }
}

// ==================== launch ====================
extern "C" void kernel_launch(void* const* d_in, const int* in_sizes, int n_in,
                              void* d_out, int out_size, void* d_ws, size_t ws_size,
                              hipStream_t stream) {
  const float* ud  = (const float*)d_in[0];
  const float* yd  = (const float*)d_in[1];
  const float* qv  = (const float*)d_in[2];
  const float* rv  = (const float*)d_in[3];
  const float* ref = (const float*)d_in[4];
  const float* ui  = (const float*)d_in[5];
  const float* yi  = (const float*)d_in[6];
  float* out = (float*)d_out;
  char* w = (char*)d_ws;

  float*  C    = (float*)(w + OFF_C);
  double* GCC  = (double*)(w + OFF_GCC);
  double* G    = (double*)(w + OFF_G);
  double* TA   = (double*)(w + OFF_TA);
  double* S    = (double*)(w + OFF_S);
  double* X12  = (double*)(w + OFF_X12);
  float*  MRAW = (float*)(w + OFF_MRAW);
  float*  MALL = (float*)(w + OFF_MALL);
  float*  INA  = (float*)(w + OFF_INALL);
  double* ILG  = (double*)(w + OFF_ILG);
  double* ILS  = (double*)(w + OFF_ILS);
  double* IDG  = (double*)(w + OFF_IDG);
  double* IDS  = (double*)(w + OFF_IDS);
  double* WG   = (double*)(w + OFF_WG);
  double* WS   = (double*)(w + OFF_WS);
  double* LG   = (double*)(w + OFF_LG);
  double* LS   = (double*)(w + OFF_LS);
  double* TB   = (double*)(w + OFF_TB);
  double* TINV = (double*)(w + OFF_TINV);
  double* XB   = (double*)(w + OFF_XB);
  unsigned int* BAR = (unsigned int*)(w + OFF_BAR);

  k_build_C<<<dim3(8, NCRP), 256, 0, stream>>>(ud, yd, C);
  k_gram<<<dim3(24, 24), 256, 0, stream>>>(C, GCC);
  hipMemsetAsync(BAR, 0, 64, stream);  // zero the barrier counter (C-region hole)

  k_coop<<<dim3(NBLK), dim3(256), 0, stream>>>(
      GCC, G, TA, S, X12, MRAW, MALL, ILG, ILS, IDG, IDS,
      WG, WS, LG, LS, TB, TINV, XB, qv, rv, BAR);

  k_transpose_in<<<dim3(NBATCH / 32, LDMA / 32), 256, 0, stream>>>(ref, ui, yi, INA);
  k_gemm_out<<<dim3(NBATCH / 128, NG / 128), 256, 0, stream>>>(MALL, INA, out);
}

// Round 6
// 9104.762 us; speedup vs baseline: 1.4952x; 1.4952x over previous
//
#include <hip/hip_runtime.h>
#include <hip/hip_bf16.h>

// ---------------- problem constants ----------------
#define LDIM   1851   // L = TT - TINI - NH + 1
#define NFR    1000   // rows of F = [Uf(400); Yf(600)]
#define NAR    506    // rows of A = [Up(200); Yp(300); Yf_last(6)]
#define NCRP   1536   // padded rows of C = [F; A]
#define LDC    1856   // padded Hankel width
#define NG     1024   // padded G dim
#define NS     512    // padded S dim
#define NXC    1152   // padded X12 cols (1106 -> 1152)
#define LDMA   1120   // padded M_all cols (1100 -> 1120)
#define NBATCH 4096
#define NOUT   1000
#define INVDP  500000.0   // 1/(2*DELTA)
#define NBLK   240        // <= 256 CUs -> all blocks resident by construction

// ---------------- ws layout (bytes), lifetime-overlaid, total ~77.3 MB ----------------
#define OFF_C     ((size_t)0)
#define SZ_C      ((size_t)NCRP * LDC * 4)            // C dead after k_gram
#define OFF_ILG   OFF_C                               // 1024*1024*8 (over C)
#define OFF_ILS   (OFF_C + 8388608)                   // 512*512*8 (over C)
#define OFF_BAR   (OFF_C + 10485760)                  // 16KB barrier slots (C hole, after ILS)
#define OFF_GCC   (OFF_C + SZ_C)
#define SZ_GCC    ((size_t)NCRP * NCRP * 8)
#define OFF_G     (OFF_GCC + SZ_GCC)
#define SZ_G      ((size_t)NG * NG * 8)
#define OFF_TA    (OFF_G + SZ_G)
#define SZ_TA     ((size_t)NG * NS * 8)
#define OFF_S     (OFF_TA + SZ_TA)
#define SZ_S      ((size_t)NS * NS * 8)
#define OFF_X12   (OFF_S + SZ_S)
#define SZ_X12    ((size_t)NS * NXC * 8)
#define OFF_MRAW  (OFF_X12 + SZ_X12)
#define SZ_MRAW   ((size_t)NG * NXC * 4)
#define OFF_XB    OFF_MRAW                            // XB dead before MRAW written
#define OFF_MALL  (OFF_MRAW + SZ_MRAW)
#define SZ_MALL   ((size_t)NG * LDMA * 4)             // written at very end of coop
#define OFF_IDG   OFF_MALL                            // 16*4096*8
#define OFF_IDS   (OFF_MALL + 524288)                 // 8*4096*8
#define OFF_WG    (OFF_MALL + 786432)                 // 16*4096*8
#define OFF_WS    (OFF_MALL + 1310720)                // 8*4096*8
#define OFF_LS    (OFF_MALL + 1572864)                // 512*512*8 (ends 3.67MB < 4.59MB)
#define OFF_INALL (OFF_MALL + SZ_MALL)
#define SZ_INALL  ((size_t)LDMA * NBATCH * 4)         // written late by transpose
#define OFF_TB    OFF_INALL                           // 1024*512*8
#define OFF_TINV  (OFF_INALL + 4194304)               // 512*512*8
#define OFF_LG    (OFF_INALL + 6291456)               // 1024*1024*8 (ends 14.68MB < 18.35MB)

__device__ __forceinline__ double dweight(int i, const float* q, const float* r) {
  return (i < 400) ? (double)r[i] : (double)q[i - 400];
}

// ==================== contention-free software grid barrier ====================
// bar layout (uints): arrive[b] at bar[b*16] (64B stride, one line per block),
// release flag at bar[NBLK*16]. Zeroed by hipMemsetAsync each launch.
// No RMWs: per-block RELEASE store to own slot; block 0 gathers with parallel
// RELAXED polls (one slot per thread), fences, RELEASE-stores the release word;
// other blocks RELAXED-poll release. Happens-before is transitive via block 0.
__device__ __forceinline__ void gbar(unsigned int* bar, unsigned int* phase) {
  __syncthreads();
  __threadfence();
  unsigned int ph = ++(*phase);
  if (blockIdx.x == 0) {
    int t = threadIdx.x;
    if (t >= 1 && t < (int)gridDim.x) {
      while (__hip_atomic_load(&bar[t * 16], __ATOMIC_RELAXED, __HIP_MEMORY_SCOPE_AGENT) < ph) {
        __builtin_amdgcn_s_sleep(2);
      }
    }
    __syncthreads();
    __threadfence();
    if (threadIdx.x == 0)
      __hip_atomic_store(&bar[NBLK * 16], ph, __ATOMIC_RELEASE, __HIP_MEMORY_SCOPE_AGENT);
  } else {
    if (threadIdx.x == 0) {
      __hip_atomic_store(&bar[blockIdx.x * 16], ph, __ATOMIC_RELEASE, __HIP_MEMORY_SCOPE_AGENT);
      while (__hip_atomic_load(&bar[NBLK * 16], __ATOMIC_RELAXED, __HIP_MEMORY_SCOPE_AGENT) < ph) {
        __builtin_amdgcn_s_sleep(2);
      }
    }
  }
  __threadfence();
  __syncthreads();
}

// ==================== standalone kernels ====================

__global__ __launch_bounds__(256) void k_build_C(const float* __restrict__ ud,
                                                 const float* __restrict__ yd,
                                                 float* __restrict__ C) {
  int j = blockIdx.x * 256 + threadIdx.x;
  int rr = blockIdx.y;
  if (j >= LDC) return;
  float v = 0.f;
  if (j < LDIM) {
    if (rr < 400)        v = ud[200 + rr + 4 * j];            // Uf
    else if (rr < 1000)  v = yd[300 + (rr - 400) + 6 * j];    // Yf
    else if (rr < 1200)  v = ud[(rr - 1000) + 4 * j];         // Up
    else if (rr < 1500)  v = yd[(rr - 1200) + 6 * j];         // Yp
    else if (rr < 1506)  v = yd[894 + (rr - 1500) + 6 * j];   // Yf[-P:]
  }
  C[(size_t)rr * LDC + j] = v;
}

// GCC = C * C^T, fp64 accumulation (64x64 lower tiles + mirror) — R2-proven version
__global__ __launch_bounds__(256) void k_gram(const float* __restrict__ C,
                                              double* __restrict__ GCC) {
  int ti = blockIdx.y, tj = blockIdx.x;
  if (ti < tj) return;
  __shared__ float As[64][33];
  __shared__ float Bs[64][33];
  int tid = threadIdx.x;
  int tr4 = (tid >> 4) * 4, tc4 = (tid & 15) * 4;
  double acc[4][4] = {};
  int i0 = ti * 64, j0 = tj * 64;
  for (int k0 = 0; k0 < LDC; k0 += 32) {
#pragma unroll
    for (int l = 0; l < 8; ++l) {
      int t = tid + l * 256;
      int rr = t >> 5, cc = t & 31;
      As[rr][cc] = C[(size_t)(i0 + rr) * LDC + k0 + cc];
      Bs[rr][cc] = C[(size_t)(j0 + rr) * LDC + k0 + cc];
    }
    __syncthreads();
#pragma unroll
    for (int kk = 0; kk < 32; ++kk) {
      double a[4], b[4];
#pragma unroll
      for (int i = 0; i < 4; ++i) a[i] = (double)As[tr4 + i][kk];
#pragma unroll
      for (int jx = 0; jx < 4; ++jx) b[jx] = (double)Bs[tc4 + jx][kk];
#pragma unroll
      for (int i = 0; i < 4; ++i)
#pragma unroll
        for (int jx = 0; jx < 4; ++jx) acc[i][jx] += a[i] * b[jx];
    }
    __syncthreads();
  }
#pragma unroll
  for (int i = 0; i < 4; ++i)
#pragma unroll
    for (int jx = 0; jx < 4; ++jx) {
      int gi = i0 + tr4 + i, gj = j0 + tc4 + jx;
      GCC[(size_t)gi * NCRP + gj] = acc[i][jx];
      if (ti != tj) GCC[(size_t)gj * NCRP + gi] = acc[i][jx];
    }
}

__global__ __launch_bounds__(256) void k_transpose_in(const float* __restrict__ ref,
                                                      const float* __restrict__ ui,
                                                      const float* __restrict__ yi,
                                                      float* __restrict__ INall) {
  __shared__ float t[32][33];
  int tx = threadIdx.x & 31, ty = threadIdx.x >> 5;  // 32 x 8
  int n0 = blockIdx.x * 32, j0 = blockIdx.y * 32;
#pragma unroll
  for (int p = 0; p < 4; ++p) {
    int nb = n0 + ty + p * 8;
    int j = j0 + tx;
    float v = 0.f;
    if (j < 600)        v = ref[(size_t)nb * 600 + j];
    else if (j < 800)   v = ui[(size_t)nb * 200 + (j - 600)];
    else if (j < 1100)  v = yi[(size_t)nb * 300 + (j - 800)];
    t[ty + p * 8][tx] = v;
  }
  __syncthreads();
#pragma unroll
  for (int p = 0; p < 4; ++p) {
    INall[(size_t)(j0 + ty + p * 8) * NBATCH + n0 + tx] = t[tx][ty + p * 8];
  }
}

__global__ __launch_bounds__(256) void k_gemm_out(const float* __restrict__ Mall,
                                                  const float* __restrict__ INall,
                                                  float* __restrict__ out) {
  __shared__ float As[32][132];
  __shared__ float Bs[32][132];
  int tid = threadIdx.x;
  int tr = tid >> 4, tc = tid & 15;
  int m0 = blockIdx.y * 128, n0 = blockIdx.x * 128;
  float acc[8][8] = {};
  for (int k0 = 0; k0 < LDMA; k0 += 32) {
#pragma unroll
    for (int l = 0; l < 16; ++l) {
      int t = tid + l * 256;
      int rr = t >> 5, cc = t & 31;
      As[cc][rr] = Mall[(size_t)(m0 + rr) * LDMA + k0 + cc];
    }
#pragma unroll
    for (int l = 0; l < 16; ++l) {
      int t = tid + l * 256;
      int rr = t >> 7, cc = t & 127;
      Bs[rr][cc] = INall[(size_t)(k0 + rr) * NBATCH + n0 + cc];
    }
    __syncthreads();
#pragma unroll
    for (int kk = 0; kk < 32; ++kk) {
      float4 a0 = *(const float4*)&As[kk][tr * 4];
      float4 a1 = *(const float4*)&As[kk][64 + tr * 4];
      float4 b0 = *(const float4*)&Bs[kk][tc * 4];
      float4 b1 = *(const float4*)&Bs[kk][64 + tc * 4];
      float av[8] = {a0.x, a0.y, a0.z, a0.w, a1.x, a1.y, a1.z, a1.w};
      float bv[8] = {b0.x, b0.y, b0.z, b0.w, b1.x, b1.y, b1.z, b1.w};
#pragma unroll
      for (int i = 0; i < 8; ++i)
#pragma unroll
        for (int jx = 0; jx < 8; ++jx) acc[i][jx] += av[i] * bv[jx];
    }
    __syncthreads();
  }
#pragma unroll
  for (int ih = 0; ih < 2; ++ih)
#pragma unroll
    for (int i = 0; i < 4; ++i) {
      int o = m0 + ih * 64 + tr * 4 + i;
      if (o < NOUT) {
#pragma unroll
        for (int jh = 0; jh < 2; ++jh) {
          float4 v = make_float4(acc[ih * 4 + i][jh * 4 + 0], acc[ih * 4 + i][jh * 4 + 1],
                                 acc[ih * 4 + i][jh * 4 + 2], acc[ih * 4 + i][jh * 4 + 3]);
          *(float4*)&out[(size_t)o * NBATCH + n0 + jh * 64 + tc * 4] = v;
        }
      }
    }
}

// ==================== device cores (shared pool: 6400 doubles = 51.2 KB) ====================

// R2-proven: factor 64x64 tile resident in sm (stride 65, pre-loaded + synced);
// invd[] at sm+4160. Writes L tile to Ldst (upper junk, never read), inv(L) to
// iLout (zeros above diag), W = iL^T iL to Wout.
__device__ __forceinline__ void potrf_inv_w(double* sm, int tid,
                                            double* Ldst, int ld,
                                            double* iLout, double* Wout) {
  double* invd = sm + 4160;
  for (int c = 0; c < 64; ++c) {
    if (tid == 0) sm[c * 65 + c] = sqrt(sm[c * 65 + c]);
    __syncthreads();
    double piv = sm[c * 65 + c];
    for (int rr = c + 1 + tid; rr < 64; rr += 256) sm[rr * 65 + c] /= piv;
    __syncthreads();
    for (int t = tid; t < 64 * 64; t += 256) {
      int rr = t >> 6, jj = t & 63;
      if (rr > c && jj > c) sm[rr * 65 + jj] -= sm[rr * 65 + c] * sm[jj * 65 + c];
    }
    __syncthreads();
  }
#pragma unroll
  for (int l = 0; l < 16; ++l) {
    int t = tid + l * 256;
    Ldst[(size_t)(t >> 6) * ld + (t & 63)] = sm[(t >> 6) * 65 + (t & 63)];
  }
  __syncthreads();
  if (tid < 64) invd[tid] = 1.0 / sm[tid * 65 + tid];
  __syncthreads();
  if (tid < 64) {            // thread c solves column c of inv(L) into upper of sm
    int c = tid;
    for (int r = c + 1; r < 64; ++r) {
      double s = sm[r * 65 + c] * invd[c];
      for (int j = c + 1; j < r; ++j) s += sm[r * 65 + j] * sm[c * 65 + j];
      sm[c * 65 + r] = -s * invd[r];
    }
  }
  __syncthreads();
#pragma unroll
  for (int l = 0; l < 16; ++l) {
    int t = tid + l * 256;
    int r = t >> 6, c = t & 63;
    iLout[t] = (r < c) ? 0.0 : (r == c ? invd[r] : sm[c * 65 + r]);
  }
  for (int idx = tid; idx < 4096; idx += 256) {   // W = iL^T iL
    int r = idx >> 6, c = idx & 63;
    int k2 = r > c ? r : c;
    double s = 0.0;
    for (; k2 < 64; ++k2) {
      double ar = (k2 == r) ? invd[r] : sm[r * 65 + k2];
      double ac = (k2 == c) ? invd[c] : sm[c * 65 + k2];
      s += ar * ac;
    }
    Wout[idx] = s;
  }
}

// fused panel step: block t < nbp*(nbp+1)/2 handles trailing tile (i,j);
// j==0 blocks also emit the L21 panel tile; block 0 then factors next diagonal.
#define PFS1(r, c) sm[(r) * 65 + (c)]
#define PFS2(r, c) sm[4288 + (r) * 33 + (c)]
__device__ __forceinline__ void chol_panel(double* sm, double* M, int ld, int k, int nbp,
                                           const double* iLcur, const double* Wcur,
                                           double* LGm, double* iLnext, double* Wnext) {
  int tid = threadIdx.x;
  int t = blockIdx.x;
  int tiles = nbp * (nbp + 1) / 2;
  if (t >= tiles) return;
  int i = 0;
  while ((i + 1) * (i + 2) / 2 <= t) ++i;
  int j = t - i * (i + 1) / 2;
  int tr4 = (tid >> 4) * 4, tc4 = (tid & 15) * 4;
  int rowAi = k + 64 + i * 64, rowAj = k + 64 + j * 64;

  // Phase A (j==0): Li = Ai * iL^T  -> LG panel
  if (j == 0) {
#pragma unroll
    for (int l = 0; l < 16; ++l) { int t2 = tid + l * 256; PFS1(t2 >> 6, t2 & 63) = iLcur[t2]; }
    __syncthreads();
    double li[4][4] = {};
    for (int k0 = 0; k0 < 64; k0 += 32) {
#pragma unroll
      for (int l = 0; l < 8; ++l) {
        int t2 = tid + l * 256;
        PFS2(t2 >> 5, t2 & 31) = M[(size_t)(rowAi + (t2 >> 5)) * ld + k + k0 + (t2 & 31)];
      }
      __syncthreads();
#pragma unroll
      for (int mm = 0; mm < 32; ++mm) {
        double a[4], b[4];
#pragma unroll
        for (int i2 = 0; i2 < 4; ++i2) a[i2] = PFS2(tr4 + i2, mm);
#pragma unroll
        for (int j2 = 0; j2 < 4; ++j2) b[j2] = PFS1(tc4 + j2, k0 + mm);
#pragma unroll
        for (int i2 = 0; i2 < 4; ++i2)
#pragma unroll
          for (int j2 = 0; j2 < 4; ++j2) li[i2][j2] += a[i2] * b[j2];
      }
      __syncthreads();
    }
#pragma unroll
    for (int i2 = 0; i2 < 4; ++i2)
#pragma unroll
      for (int j2 = 0; j2 < 4; ++j2)
        LGm[(size_t)(rowAi + tr4 + i2) * ld + k + tc4 + j2] = li[i2][j2];
  }
  __syncthreads();

  // Phase B: tile (i,j) -= Ai * W * Aj^T
#pragma unroll
  for (int l = 0; l < 16; ++l) { int t2 = tid + l * 256; PFS1(t2 >> 6, t2 & 63) = Wcur[t2]; }
  __syncthreads();
  double acc[4][4] = {};
  for (int k0 = 0; k0 < 64; k0 += 32) {   // D1 = W * Aj^T
#pragma unroll
    for (int l = 0; l < 8; ++l) {
      int t2 = tid + l * 256;
      PFS2(t2 >> 5, t2 & 31) = M[(size_t)(rowAj + (t2 >> 5)) * ld + k + k0 + (t2 & 31)];
    }
    __syncthreads();
#pragma unroll
    for (int mm = 0; mm < 32; ++mm) {
      double a[4], b[4];
#pragma unroll
      for (int i2 = 0; i2 < 4; ++i2) a[i2] = PFS1(tr4 + i2, k0 + mm);
#pragma unroll
      for (int j2 = 0; j2 < 4; ++j2) b[j2] = PFS2(tc4 + j2, mm);
#pragma unroll
      for (int i2 = 0; i2 < 4; ++i2)
#pragma unroll
        for (int j2 = 0; j2 < 4; ++j2) acc[i2][j2] += a[i2] * b[j2];
    }
    __syncthreads();
  }
#pragma unroll
  for (int i2 = 0; i2 < 4; ++i2)   // stash D1 over dead W
#pragma unroll
    for (int j2 = 0; j2 < 4; ++j2) PFS1(tr4 + i2, tc4 + j2) = acc[i2][j2];
  __syncthreads();
  double acc2[4][4] = {};
  for (int k0 = 0; k0 < 64; k0 += 32) {   // C2 = Ai * D1
#pragma unroll
    for (int l = 0; l < 8; ++l) {
      int t2 = tid + l * 256;
      PFS2(t2 >> 5, t2 & 31) = M[(size_t)(rowAi + (t2 >> 5)) * ld + k + k0 + (t2 & 31)];
    }
    __syncthreads();
#pragma unroll
    for (int mm = 0; mm < 32; ++mm) {
      double a[4], b[4];
#pragma unroll
      for (int i2 = 0; i2 < 4; ++i2) a[i2] = PFS2(tr4 + i2, mm);
#pragma unroll
      for (int j2 = 0; j2 < 4; ++j2) b[j2] = PFS1(k0 + mm, tc4 + j2);
#pragma unroll
      for (int i2 = 0; i2 < 4; ++i2)
#pragma unroll
        for (int j2 = 0; j2 < 4; ++j2) acc2[i2][j2] += a[i2] * b[j2];
    }
    __syncthreads();
  }
  double upd[4][4];
#pragma unroll
  for (int i2 = 0; i2 < 4; ++i2)
#pragma unroll
    for (int j2 = 0; j2 < 4; ++j2) {
      size_t off = (size_t)(rowAi + tr4 + i2) * ld + rowAj + tc4 + j2;
      upd[i2][j2] = M[off] - acc2[i2][j2];
      M[off] = upd[i2][j2];
    }

  // Phase C (block 0 == tile (0,0) == next diagonal)
  if (t == 0) {
    __syncthreads();
#pragma unroll
    for (int i2 = 0; i2 < 4; ++i2)
#pragma unroll
      for (int j2 = 0; j2 < 4; ++j2) PFS1(tr4 + i2, tc4 + j2) = upd[i2][j2];
    __syncthreads();
    potrf_inv_w(sm, tid, LGm + (size_t)(k + 64) * ld + (k + 64), ld, iLnext, Wnext);
  }
}

// generic fp64 GEMM cores on the shared pool (64x64 C tile, 4x4 micro)
__device__ __forceinline__ void dgemm_nn_core(double* sm, const double* A, int lda,
                                              const double* B, int ldb,
                                              double* C, int ldc,
                                              int kBeg, int kEnd, double alpha) {
  double* As = sm;          // 64x33
  double* Bs = sm + 2112;   // 32x65
  int tid = threadIdx.x;
  int tr4 = (tid >> 4) * 4, tc4 = (tid & 15) * 4;
  double acc[4][4] = {};
  for (int k0 = kBeg; k0 < kEnd; k0 += 32) {
#pragma unroll
    for (int l = 0; l < 8; ++l) {
      int t = tid + l * 256;
      As[(t >> 5) * 33 + (t & 31)] = A[(size_t)(t >> 5) * lda + k0 + (t & 31)];
    }
#pragma unroll
    for (int l = 0; l < 8; ++l) {
      int t = tid + l * 256;
      Bs[(t >> 6) * 65 + (t & 63)] = B[(size_t)(k0 + (t >> 6)) * ldb + (t & 63)];
    }
    __syncthreads();
#pragma unroll
    for (int kk = 0; kk < 32; ++kk) {
      double a[4], b[4];
#pragma unroll
      for (int i = 0; i < 4; ++i) a[i] = As[(tr4 + i) * 33 + kk];
#pragma unroll
      for (int jx = 0; jx < 4; ++jx) b[jx] = Bs[kk * 65 + tc4 + jx];
#pragma unroll
      for (int i = 0; i < 4; ++i)
#pragma unroll
        for (int jx = 0; jx < 4; ++jx) acc[i][jx] += a[i] * b[jx];
    }
    __syncthreads();
  }
#pragma unroll
  for (int i = 0; i < 4; ++i)
#pragma unroll
    for (int jx = 0; jx < 4; ++jx)
      C[(size_t)(tr4 + i) * ldc + tc4 + jx] = alpha * acc[i][jx];
}

__device__ __forceinline__ void dgemm_tn_core(double* sm, const double* A, int lda,
                                              const double* B, int ldb,
                                              double* C, int ldc,
                                              int kBeg, int kEnd, double alpha) {
  double* Ls = sm;          // 32x65
  double* Bs = sm + 2080;   // 32x65
  int tid = threadIdx.x;
  int tr4 = (tid >> 4) * 4, tc4 = (tid & 15) * 4;
  double acc[4][4] = {};
  for (int k0 = kBeg; k0 < kEnd; k0 += 32) {
#pragma unroll
    for (int l = 0; l < 8; ++l) {
      int t = tid + l * 256;
      Ls[(t >> 6) * 65 + (t & 63)] = A[(size_t)(k0 + (t >> 6)) * lda + (t & 63)];
    }
#pragma unroll
    for (int l = 0; l < 8; ++l) {
      int t = tid + l * 256;
      Bs[(t >> 6) * 65 + (t & 63)] = B[(size_t)(k0 + (t >> 6)) * ldb + (t & 63)];
    }
    __syncthreads();
#pragma unroll
    for (int kk = 0; kk < 32; ++kk) {
      double a[4], b[4];
#pragma unroll
      for (int i = 0; i < 4; ++i) a[i] = Ls[kk * 65 + tr4 + i];
#pragma unroll
      for (int jx = 0; jx < 4; ++jx) b[jx] = Bs[kk * 65 + tc4 + jx];
#pragma unroll
      for (int i = 0; i < 4; ++i)
#pragma unroll
        for (int jx = 0; jx < 4; ++jx) acc[i][jx] += a[i] * b[jx];
    }
    __syncthreads();
  }
#pragma unroll
  for (int i = 0; i < 4; ++i)
#pragma unroll
    for (int jx = 0; jx < 4; ++jx)
      C[(size_t)(tr4 + i) * ldc + tc4 + jx] = alpha * acc[i][jx];
}

__device__ __forceinline__ void buildS_tile(double* sm, const double* GCC,
                                            const double* TA, double* S, int t) {
  double* Ga = sm;          // 64x33
  double* Tb = sm + 2112;   // 32x65
  int tid = threadIdx.x;
  int tr4 = (tid >> 4) * 4, tc4 = (tid & 15) * 4;
  int a0 = (t >> 3) * 64, b0 = (t & 7) * 64;
  double acc[4][4] = {};
  for (int f0 = 0; f0 < NG; f0 += 32) {
#pragma unroll
    for (int l = 0; l < 8; ++l) {
      int t2 = tid + l * 256;
      Ga[(t2 >> 5) * 33 + (t2 & 31)] = GCC[(size_t)(1000 + a0 + (t2 >> 5)) * NCRP + f0 + (t2 & 31)];
    }
#pragma unroll
    for (int l = 0; l < 8; ++l) {
      int t2 = tid + l * 256;
      Tb[(t2 >> 6) * 65 + (t2 & 63)] = TA[(size_t)(f0 + (t2 >> 6)) * NS + b0 + (t2 & 63)];
    }
    __syncthreads();
#pragma unroll
    for (int kk = 0; kk < 32; ++kk) {
      double a[4], b[4];
#pragma unroll
      for (int i = 0; i < 4; ++i) a[i] = Ga[(tr4 + i) * 33 + kk];
#pragma unroll
      for (int jx = 0; jx < 4; ++jx) b[jx] = Tb[kk * 65 + tc4 + jx];
#pragma unroll
      for (int i = 0; i < 4; ++i)
#pragma unroll
        for (int jx = 0; jx < 4; ++jx) acc[i][jx] += a[i] * b[jx];
    }
    __syncthreads();
  }
#pragma unroll
  for (int i = 0; i < 4; ++i)
#pragma unroll
    for (int jx = 0; jx < 4; ++jx) {
      int a = a0 + tr4 + i, b = b0 + tc4 + jx;
      double v;
      if (a < NAR && b < NAR)
        v = (GCC[(size_t)(1000 + a) * NCRP + 1000 + b] - acc[i][jx]) * INVDP;
      else
        v = (a == b) ? 1.0 : 0.0;
      S[(size_t)a * NS + b] = v;
    }
}

__device__ __forceinline__ void gemmM_tile(double* sm, const double* TA, const double* X12,
                                           const float* q, const float* r,
                                           float* Mraw, int t) {
  double* Ga = sm;          // 64x33
  double* Xb = sm + 2112;   // 32x65
  int tid = threadIdx.x;
  int tr4 = (tid >> 4) * 4, tc4 = (tid & 15) * 4;
  int o0 = (t / 18) * 64, c0 = (t % 18) * 64;
  double acc[4][4] = {};
  for (int k0 = 0; k0 < NS; k0 += 32) {
#pragma unroll
    for (int l = 0; l < 8; ++l) {
      int t2 = tid + l * 256;
      Ga[(t2 >> 5) * 33 + (t2 & 31)] = TA[(size_t)(o0 + (t2 >> 5)) * NS + k0 + (t2 & 31)];
    }
#pragma unroll
    for (int l = 0; l < 8; ++l) {
      int t2 = tid + l * 256;
      Xb[(t2 >> 6) * 65 + (t2 & 63)] = X12[(size_t)(k0 + (t2 >> 6)) * NXC + c0 + (t2 & 63)];
    }
    __syncthreads();
#pragma unroll
    for (int kk = 0; kk < 32; ++kk) {
      double a[4], b[4];
#pragma unroll
      for (int i = 0; i < 4; ++i) a[i] = Ga[(tr4 + i) * 33 + kk];
#pragma unroll
      for (int jx = 0; jx < 4; ++jx) b[jx] = Xb[kk * 65 + tc4 + jx];
#pragma unroll
      for (int i = 0; i < 4; ++i)
#pragma unroll
        for (int jx = 0; jx < 4; ++jx) acc[i][jx] += a[i] * b[jx];
    }
    __syncthreads();
  }
#pragma unroll
  for (int i = 0; i < 4; ++i)
#pragma unroll
    for (int jx = 0; jx < 4; ++jx) {
      int o = o0 + tr4 + i, col = c0 + tc4 + jx;
      float v = 0.f;
      if (o < NFR) {
        double scale = 1.0 / (2.0 * dweight(o, q, r));
        double tt = acc[i][jx] * scale;
        v = (float)((col < 600) ? -tt : tt);
      }
      Mraw[(size_t)o * NXC + col] = v;
    }
}

// ==================== the single-chain kernel (software grid barrier) ====================
__global__ __launch_bounds__(256) void k_coop(
    double* GCC, double* G, double* TA, double* S, double* X12,
    float* MRAW, float* MALL,
    double* ILG, double* ILS, double* IDG, double* IDS,
    double* WG, double* WS, double* LG, double* LS,
    double* TB, double* TINV, double* XB,
    const float* qv, const float* rv, unsigned int* bar) {
  __shared__ double sm[6400];  // 51.2 KB pool shared by all stage cores
  const int tid = threadIdx.x;
  const int bid = blockIdx.x;
  const int nbk = gridDim.x;
  const int gsz = nbk * 256;
  const int gix = bid * 256 + tid;
  unsigned int phase = 0;

  // ---- S1: G = GFF + (1e-6/d) I (identity-padded); TA = F A^T (zero-padded) ----
  for (int idx = gix; idx < NG * NG; idx += gsz) {
    int i = idx >> 10, j = idx & 1023;
    double v = (i < NFR && j < NFR) ? GCC[(size_t)i * NCRP + j] : 0.0;
    if (i == j) v = (i < NFR) ? v + 1e-6 / dweight(i, qv, rv) : 1.0;
    G[idx] = v;
  }
  for (int idx = gix; idx < NG * NS; idx += gsz) {
    int f = idx >> 9, a = idx & 511;
    TA[idx] = (f < NFR && a < NAR) ? GCC[(size_t)f * NCRP + 1000 + a] : 0.0;
  }
  gbar(bar, &phase);

  // ---- S2: Cholesky of G (16 panels) ----
  if (bid == 0) {
    for (int l = 0; l < 16; ++l) {
      int t2 = tid + l * 256;
      sm[(t2 >> 6) * 65 + (t2 & 63)] = G[(size_t)(t2 >> 6) * NG + (t2 & 63)];
    }
    __syncthreads();
    potrf_inv_w(sm, tid, LG, NG, IDG, WG);
  }
  gbar(bar, &phase);
  for (int p = 0; p < 15; ++p) {
    chol_panel(sm, G, NG, p * 64, 15 - p, IDG + (size_t)p * 4096, WG + (size_t)p * 4096,
               LG, IDG + (size_t)(p + 1) * 4096, WG + (size_t)(p + 1) * 4096);
    gbar(bar, &phase);
  }

  // ---- S3: iL_G via D&C (log depth) ----
  for (int idx = gix; idx < NG * NG; idx += gsz) {
    int i = idx >> 10, j = idx & 1023;
    int d = i >> 6;
    ILG[idx] = ((j >> 6) == d) ? IDG[(size_t)d * 4096 + (i & 63) * 64 + (j & 63)] : 0.0;
  }
  gbar(bar, &phase);
  for (int lv = 0; lv < 4; ++lv) {
    int half = 64 << lv, pairs = NG / (2 * half), hb = half >> 6;
    int tiles = pairs * hb * hb;
    for (int t = bid; t < tiles; t += nbk) {
      int p = t / (hb * hb), rem = t % (hb * hb), bi = rem / hb, bj = rem % hb;
      int base = p * 2 * half;
      dgemm_nn_core(sm, LG + (size_t)(base + half + bi * 64) * NG + base, NG,
                    ILG + (size_t)base * NG + base + bj * 64, NG,
                    TINV + (size_t)p * half * half + (size_t)bi * 64 * half + bj * 64, half,
                    0, half, 1.0);
    }
    gbar(bar, &phase);
    for (int t = bid; t < tiles; t += nbk) {
      int p = t / (hb * hb), rem = t % (hb * hb), bi = rem / hb, bj = rem % hb;
      int base = p * 2 * half;
      dgemm_nn_core(sm, ILG + (size_t)(base + half + bi * 64) * NG + base + half, NG,
                    TINV + (size_t)p * half * half + bj * 64, half,
                    ILG + (size_t)(base + half + bi * 64) * NG + base + bj * 64, NG,
                    0, half, -1.0);
    }
    gbar(bar, &phase);
  }

  // ---- S4: TA <- iL^T (iL TA)  (triangle-aware K ranges) ----
  for (int t = bid; t < 128; t += nbk) {
    int bi = t >> 3, bj = t & 7;
    dgemm_nn_core(sm, ILG + (size_t)bi * 64 * NG, NG, TA + bj * 64, NS,
                  TB + (size_t)bi * 64 * NS + bj * 64, NS, 0, (bi + 1) * 64, 1.0);
  }
  gbar(bar, &phase);
  for (int t = bid; t < 128; t += nbk) {
    int bi = t >> 3, bj = t & 7;
    dgemm_tn_core(sm, ILG + bi * 64, NG, TB + bj * 64, NS,
                  TA + (size_t)bi * 64 * NS + bj * 64, NS, bi * 64, NG, 1.0);
  }
  gbar(bar, &phase);

  // ---- S5: S = (GAA - GAF*TA)/(2*DELTA) ----
  for (int t = bid; t < 64; t += nbk) buildS_tile(sm, GCC, TA, S, t);
  gbar(bar, &phase);

  // ---- S6: Cholesky of S (8 panels) ----
  if (bid == 0) {
    for (int l = 0; l < 16; ++l) {
      int t2 = tid + l * 256;
      sm[(t2 >> 6) * 65 + (t2 & 63)] = S[(size_t)(t2 >> 6) * NS + (t2 & 63)];
    }
    __syncthreads();
    potrf_inv_w(sm, tid, LS, NS, IDS, WS);
  }
  gbar(bar, &phase);
  for (int p = 0; p < 7; ++p) {
    chol_panel(sm, S, NS, p * 64, 7 - p, IDS + (size_t)p * 4096, WS + (size_t)p * 4096,
               LS, IDS + (size_t)(p + 1) * 4096, WS + (size_t)(p + 1) * 4096);
    gbar(bar, &phase);
  }

  // ---- S7: iL_S via D&C ----
  for (int idx = gix; idx < NS * NS; idx += gsz) {
    int i = idx >> 9, j = idx & 511;
    int d = i >> 6;
    ILS[idx] = ((j >> 6) == d) ? IDS[(size_t)d * 4096 + (i & 63) * 64 + (j & 63)] : 0.0;
  }
  gbar(bar, &phase);
  for (int lv = 0; lv < 3; ++lv) {
    int half = 64 << lv, pairs = NS / (2 * half), hb = half >> 6;
    int tiles = pairs * hb * hb;
    for (int t = bid; t < tiles; t += nbk) {
      int p = t / (hb * hb), rem = t % (hb * hb), bi = rem / hb, bj = rem % hb;
      int base = p * 2 * half;
      dgemm_nn_core(sm, LS + (size_t)(base + half + bi * 64) * NS + base, NS,
                    ILS + (size_t)base * NS + base + bj * 64, NS,
                    TINV + (size_t)p * half * half + (size_t)bi * 64 * half + bj * 64, half,
                    0, half, 1.0);
    }
    gbar(bar, &phase);
    for (int t = bid; t < tiles; t += nbk) {
      int p = t / (hb * hb), rem = t % (hb * hb), bi = rem / hb, bj = rem % hb;
      int base = p * 2 * half;
      dgemm_nn_core(sm, ILS + (size_t)(base + half + bi * 64) * NS + base + half, NS,
                    TINV + (size_t)p * half * half + bj * 64, half,
                    ILS + (size_t)(base + half + bi * 64) * NS + base + bj * 64, NS,
                    0, half, -1.0);
    }
    gbar(bar, &phase);
  }

  // ---- S8: X12 = S^{-1} [TAq^T | I] ----
  for (int a = bid; a < NS; a += nbk)
    for (int c = tid; c < NXC; c += 256) {
      double v = 0.0;
      if (a < NAR) {
        if (c < 600) v = TA[(size_t)(400 + c) * NS + a];
        else if (c < 1106) v = (a == (c - 600)) ? 1.0 : 0.0;
      }
      X12[(size_t)a * NXC + c] = v;
    }
  gbar(bar, &phase);
  for (int t = bid; t < 8 * 18; t += nbk) {
    int bi = t / 18, bj = t % 18;
    dgemm_nn_core(sm, ILS + (size_t)bi * 64 * NS, NS, X12 + bj * 64, NXC,
                  XB + (size_t)bi * 64 * NXC + bj * 64, NXC, 0, (bi + 1) * 64, 1.0);
  }
  gbar(bar, &phase);
  for (int t = bid; t < 8 * 18; t += nbk) {
    int bi = t / 18, bj = t % 18;
    dgemm_tn_core(sm, ILS + bi * 64, NS, XB + bj * 64, NXC,
                  X12 + (size_t)bi * 64 * NXC + bj * 64, NXC, bi * 64, NS, 1.0);
  }
  gbar(bar, &phase);

  // ---- S9: Mraw ----
  for (int t = bid; t < 16 * 18; t += nbk) gemmM_tile(sm, TA, X12, qv, rv, MRAW, t);
  gbar(bar, &phase);

  // ---- S10: assemble fp32 map ----
  for (int o = bid; o < NG; o += nbk)
    for (int j2 = tid; j2 < LDMA; j2 += 256) {
      float v = 0.f;
      if (j2 < 600) {
        v = MRAW[(size_t)o * NXC + j2];
        if (o == 400 + j2) v += 1.0f;
        if (j2 >= 594) v += MRAW[(size_t)o * NXC + 1100 + (j2 - 594)];
      } else if (j2 < 1100) {
        v = MRAW[(size_t)o * NXC + j2];
      }
      MALL[(size_t)o * LDMA + j2] = v;
    }
}

// ==================== launch ====================
extern "C" void kernel_launch(void* const* d_in, const int* in_sizes, int n_in,
                              void* d_out, int out_size, void* d_ws, size_t ws_size,
                              hipStream_t stream) {
  const float* ud  = (const float*)d_in[0];
  const float* yd  = (const float*)d_in[1];
  const float* qv  = (const float*)d_in[2];
  const float* rv  = (const float*)d_in[3];
  const float* ref = (const float*)d_in[4];
  const float* ui  = (const float*)d_in[5];
  const float* yi  = (const float*)d_in[6];
  float* out = (float*)d_out;
  char* w = (char*)d_ws;

  float*  C    = (float*)(w + OFF_C);
  double* GCC  = (double*)(w + OFF_GCC);
  double* G    = (double*)(w + OFF_G);
  double* TA   = (double*)(w + OFF_TA);
  double* S    = (double*)(w + OFF_S);
  double* X12  = (double*)(w + OFF_X12);
  float*  MRAW = (float*)(w + OFF_MRAW);
  float*  MALL = (float*)(w + OFF_MALL);
  float*  INA  = (float*)(w + OFF_INALL);
  double* ILG  = (double*)(w + OFF_ILG);
  double* ILS  = (double*)(w + OFF_ILS);
  double* IDG  = (double*)(w + OFF_IDG);
  double* IDS  = (double*)(w + OFF_IDS);
  double* WG   = (double*)(w + OFF_WG);
  double* WS   = (double*)(w + OFF_WS);
  double* LG   = (double*)(w + OFF_LG);
  double* LS   = (double*)(w + OFF_LS);
  double* TB   = (double*)(w + OFF_TB);
  double* TINV = (double*)(w + OFF_TINV);
  double* XB   = (double*)(w + OFF_XB);
  unsigned int* BAR = (unsigned int*)(w + OFF_BAR);

  k_build_C<<<dim3(8, NCRP), 256, 0, stream>>>(ud, yd, C);
  k_gram<<<dim3(24, 24), 256, 0, stream>>>(C, GCC);
  hipMemsetAsync(BAR, 0, 16384, stream);  // zero arrive[] + release (C-region hole)

  k_coop<<<dim3(NBLK), dim3(256), 0, stream>>>(
      GCC, G, TA, S, X12, MRAW, MALL, ILG, ILS, IDG, IDS,
      WG, WS, LG, LS, TB, TINV, XB, qv, rv, BAR);

  k_transpose_in<<<dim3(NBATCH / 32, LDMA / 32), 256, 0, stream>>>(ref, ui, yi, INA);
  k_gemm_out<<<dim3(NBATCH / 128, NG / 128), 256, 0, stream>>>(MALL, INA, out);
}

// Round 7
// 8245.573 us; speedup vs baseline: 1.6511x; 1.1042x over previous
//
#include <hip/hip_runtime.h>
#include <hip/hip_bf16.h>

// ---------------- problem constants ----------------
#define LDIM   1851   // L = TT - TINI - NH + 1
#define NFR    1000   // rows of F = [Uf(400); Yf(600)]
#define NAR    506    // rows of A = [Up(200); Yp(300); Yf_last(6)]
#define NCRP   1536   // padded rows of C = [F; A]
#define LDC    1856   // padded Hankel width
#define NG     1024   // padded G dim
#define NS     512    // padded S dim
#define NXC    1152   // padded X12 cols (1106 -> 1152)
#define LDMA   1120   // padded M_all cols (1100 -> 1120)
#define NBATCH 4096
#define NOUT   1000
#define INVDP  500000.0   // 1/(2*DELTA)
#define NBLK   240        // <= 256 CUs -> all blocks resident by construction

// ---------------- ws layout (bytes), lifetime-overlaid, total ~77.3 MB ----------------
#define OFF_C     ((size_t)0)
#define SZ_C      ((size_t)NCRP * LDC * 4)            // C dead after k_gram
#define OFF_ILG   OFF_C                               // 1024*1024*8 (over C)
#define OFF_ILS   (OFF_C + 8388608)                   // 512*512*8 (over C)
#define OFF_BAR   (OFF_C + 10485760)                  // 16KB barrier slots (C hole, after ILS)
#define OFF_GCC   (OFF_C + SZ_C)
#define SZ_GCC    ((size_t)NCRP * NCRP * 8)
#define OFF_G     (OFF_GCC + SZ_GCC)
#define SZ_G      ((size_t)NG * NG * 8)
#define OFF_TA    (OFF_G + SZ_G)
#define SZ_TA     ((size_t)NG * NS * 8)
#define OFF_S     (OFF_TA + SZ_TA)
#define SZ_S      ((size_t)NS * NS * 8)
#define OFF_X12   (OFF_S + SZ_S)
#define SZ_X12    ((size_t)NS * NXC * 8)
#define OFF_MRAW  (OFF_X12 + SZ_X12)
#define SZ_MRAW   ((size_t)NG * NXC * 4)
#define OFF_XB    OFF_MRAW                            // XB dead before MRAW written
#define OFF_MALL  (OFF_MRAW + SZ_MRAW)
#define SZ_MALL   ((size_t)NG * LDMA * 4)             // written at very end of coop
#define OFF_IDG   OFF_MALL                            // 16*4096*8
#define OFF_IDS   (OFF_MALL + 524288)                 // 8*4096*8
#define OFF_WG    (OFF_MALL + 786432)                 // 16*4096*8
#define OFF_WS    (OFF_MALL + 1310720)                // 8*4096*8
#define OFF_LS    (OFF_MALL + 1572864)                // 512*512*8 (ends 3.67MB < 4.59MB)
#define OFF_INALL (OFF_MALL + SZ_MALL)
#define SZ_INALL  ((size_t)LDMA * NBATCH * 4)         // written late by transpose
#define OFF_TB    OFF_INALL                           // 1024*512*8
#define OFF_TINV  (OFF_INALL + 4194304)               // 512*512*8
#define OFF_LG    (OFF_INALL + 6291456)               // 1024*1024*8 (ends 14.68MB < 18.35MB)

__device__ __forceinline__ double dweight(int i, const float* q, const float* r) {
  return (i < 400) ? (double)r[i] : (double)q[i - 400];
}

// ==================== software grid barrier, fence-dieted ====================
// bar layout (uints): arrive[b] at bar[b*16] (64B stride), release at bar[NBLK*16].
// Exactly ONE lane per block executes the cache ops: RELEASE store (implies one
// buffer_wbl2) and one ACQUIRE load (one buffer_inv). The preceding __syncthreads
// drains every wave's outstanding memory ops to L2 (compiler emits vmcnt(0) before
// s_barrier), so the single wbl2 publishes the whole block's writes. Block 0
// gathers arrivals with parallel relaxed polls (no fences per poll).
__device__ __forceinline__ void gbar(unsigned int* bar, unsigned int* phase) {
  unsigned int ph = ++(*phase);
  __syncthreads();
  if (blockIdx.x == 0) {
    int t = threadIdx.x;
    if (t >= 1 && t < (int)gridDim.x) {
      while (__hip_atomic_load(&bar[t * 16], __ATOMIC_RELAXED, __HIP_MEMORY_SCOPE_AGENT) < ph)
        __builtin_amdgcn_s_sleep(2);
    }
    __syncthreads();
    if (threadIdx.x == 0) {
      unsigned int d = __hip_atomic_load(&bar[16], __ATOMIC_ACQUIRE, __HIP_MEMORY_SCOPE_AGENT);
      (void)d;  // acquire -> buffer_inv (see peers' data)
      __hip_atomic_store(&bar[NBLK * 16], ph, __ATOMIC_RELEASE, __HIP_MEMORY_SCOPE_AGENT);
    }
  } else {
    if (threadIdx.x == 0) {
      __hip_atomic_store(&bar[blockIdx.x * 16], ph, __ATOMIC_RELEASE, __HIP_MEMORY_SCOPE_AGENT);
      while (__hip_atomic_load(&bar[NBLK * 16], __ATOMIC_RELAXED, __HIP_MEMORY_SCOPE_AGENT) < ph)
        __builtin_amdgcn_s_sleep(2);
      unsigned int d = __hip_atomic_load(&bar[NBLK * 16], __ATOMIC_ACQUIRE, __HIP_MEMORY_SCOPE_AGENT);
      (void)d;
    }
  }
  __syncthreads();
}

// ==================== standalone kernels ====================

__global__ __launch_bounds__(256) void k_build_C(const float* __restrict__ ud,
                                                 const float* __restrict__ yd,
                                                 float* __restrict__ C) {
  int j = blockIdx.x * 256 + threadIdx.x;
  int rr = blockIdx.y;
  if (j >= LDC) return;
  float v = 0.f;
  if (j < LDIM) {
    if (rr < 400)        v = ud[200 + rr + 4 * j];            // Uf
    else if (rr < 1000)  v = yd[300 + (rr - 400) + 6 * j];    // Yf
    else if (rr < 1200)  v = ud[(rr - 1000) + 4 * j];         // Up
    else if (rr < 1500)  v = yd[(rr - 1200) + 6 * j];         // Yp
    else if (rr < 1506)  v = yd[894 + (rr - 1500) + 6 * j];   // Yf[-P:]
  }
  C[(size_t)rr * LDC + j] = v;
}

// GCC = C * C^T, fp64 accumulation (64x64 lower tiles + mirror)
__global__ __launch_bounds__(256) void k_gram(const float* __restrict__ C,
                                              double* __restrict__ GCC) {
  int ti = blockIdx.y, tj = blockIdx.x;
  if (ti < tj) return;
  __shared__ float As[64][33];
  __shared__ float Bs[64][33];
  int tid = threadIdx.x;
  int tr4 = (tid >> 4) * 4, tc4 = (tid & 15) * 4;
  double acc[4][4] = {};
  int i0 = ti * 64, j0 = tj * 64;
  for (int k0 = 0; k0 < LDC; k0 += 32) {
#pragma unroll
    for (int l = 0; l < 8; ++l) {
      int t = tid + l * 256;
      int rr = t >> 5, cc = t & 31;
      As[rr][cc] = C[(size_t)(i0 + rr) * LDC + k0 + cc];
      Bs[rr][cc] = C[(size_t)(j0 + rr) * LDC + k0 + cc];
    }
    __syncthreads();
#pragma unroll
    for (int kk = 0; kk < 32; ++kk) {
      double a[4], b[4];
#pragma unroll
      for (int i = 0; i < 4; ++i) a[i] = (double)As[tr4 + i][kk];
#pragma unroll
      for (int jx = 0; jx < 4; ++jx) b[jx] = (double)Bs[tc4 + jx][kk];
#pragma unroll
      for (int i = 0; i < 4; ++i)
#pragma unroll
        for (int jx = 0; jx < 4; ++jx) acc[i][jx] += a[i] * b[jx];
    }
    __syncthreads();
  }
#pragma unroll
  for (int i = 0; i < 4; ++i)
#pragma unroll
    for (int jx = 0; jx < 4; ++jx) {
      int gi = i0 + tr4 + i, gj = j0 + tc4 + jx;
      GCC[(size_t)gi * NCRP + gj] = acc[i][jx];
      if (ti != tj) GCC[(size_t)gj * NCRP + gi] = acc[i][jx];
    }
}

__global__ __launch_bounds__(256) void k_transpose_in(const float* __restrict__ ref,
                                                      const float* __restrict__ ui,
                                                      const float* __restrict__ yi,
                                                      float* __restrict__ INall) {
  __shared__ float t[32][33];
  int tx = threadIdx.x & 31, ty = threadIdx.x >> 5;  // 32 x 8
  int n0 = blockIdx.x * 32, j0 = blockIdx.y * 32;
#pragma unroll
  for (int p = 0; p < 4; ++p) {
    int nb = n0 + ty + p * 8;
    int j = j0 + tx;
    float v = 0.f;
    if (j < 600)        v = ref[(size_t)nb * 600 + j];
    else if (j < 800)   v = ui[(size_t)nb * 200 + (j - 600)];
    else if (j < 1100)  v = yi[(size_t)nb * 300 + (j - 800)];
    t[ty + p * 8][tx] = v;
  }
  __syncthreads();
#pragma unroll
  for (int p = 0; p < 4; ++p) {
    INall[(size_t)(j0 + ty + p * 8) * NBATCH + n0 + tx] = t[tx][ty + p * 8];
  }
}

__global__ __launch_bounds__(256) void k_gemm_out(const float* __restrict__ Mall,
                                                  const float* __restrict__ INall,
                                                  float* __restrict__ out) {
  __shared__ float As[32][132];
  __shared__ float Bs[32][132];
  int tid = threadIdx.x;
  int tr = tid >> 4, tc = tid & 15;
  int m0 = blockIdx.y * 128, n0 = blockIdx.x * 128;
  float acc[8][8] = {};
  for (int k0 = 0; k0 < LDMA; k0 += 32) {
#pragma unroll
    for (int l = 0; l < 16; ++l) {
      int t = tid + l * 256;
      int rr = t >> 5, cc = t & 31;
      As[cc][rr] = Mall[(size_t)(m0 + rr) * LDMA + k0 + cc];
    }
#pragma unroll
    for (int l = 0; l < 16; ++l) {
      int t = tid + l * 256;
      int rr = t >> 7, cc = t & 127;
      Bs[rr][cc] = INall[(size_t)(k0 + rr) * NBATCH + n0 + cc];
    }
    __syncthreads();
#pragma unroll
    for (int kk = 0; kk < 32; ++kk) {
      float4 a0 = *(const float4*)&As[kk][tr * 4];
      float4 a1 = *(const float4*)&As[kk][64 + tr * 4];
      float4 b0 = *(const float4*)&Bs[kk][tc * 4];
      float4 b1 = *(const float4*)&Bs[kk][64 + tc * 4];
      float av[8] = {a0.x, a0.y, a0.z, a0.w, a1.x, a1.y, a1.z, a1.w};
      float bv[8] = {b0.x, b0.y, b0.z, b0.w, b1.x, b1.y, b1.z, b1.w};
#pragma unroll
      for (int i = 0; i < 8; ++i)
#pragma unroll
        for (int jx = 0; jx < 8; ++jx) acc[i][jx] += av[i] * bv[jx];
    }
    __syncthreads();
  }
#pragma unroll
  for (int ih = 0; ih < 2; ++ih)
#pragma unroll
    for (int i = 0; i < 4; ++i) {
      int o = m0 + ih * 64 + tr * 4 + i;
      if (o < NOUT) {
#pragma unroll
        for (int jh = 0; jh < 2; ++jh) {
          float4 v = make_float4(acc[ih * 4 + i][jh * 4 + 0], acc[ih * 4 + i][jh * 4 + 1],
                                 acc[ih * 4 + i][jh * 4 + 2], acc[ih * 4 + i][jh * 4 + 3]);
          *(float4*)&out[(size_t)o * NBATCH + n0 + jh * 64 + tc * 4] = v;
        }
      }
    }
}

// ==================== device cores (shared pool: 6400 doubles = 51.2 KB) ====================

// potrf-lite: factor 64x64 tile in sm (stride 65, pre-loaded + synced).
// Redundant per-thread sqrt (no tid0 serialization); diag[] at sm+4160,
// invd[] at sm+4224; lower-triangle-only trailing update (upper keeps original
// symmetric values until the inversion overwrites it; never read in between).
// Writes L to Ldst (diag from diag[], upper junk never read), inv(L) to iLout,
// W = iL^T iL to Wout.
__device__ __forceinline__ void potrf_inv_w(double* sm, int tid,
                                            double* Ldst, int ld,
                                            double* iLout, double* Wout) {
  double* diag = sm + 4160;
  double* invd = sm + 4224;
  for (int c = 0; c < 64; ++c) {
    double piv = sqrt(sm[c * 65 + c]);
    double rp = 1.0 / piv;
    if (tid == 0) diag[c] = piv;
    for (int rr = c + 1 + tid; rr < 64; rr += 256) sm[rr * 65 + c] *= rp;
    __syncthreads();
    for (int t = tid; t < 64 * 64; t += 256) {
      int rr = t >> 6, jj = t & 63;
      if (rr > c && jj > c && jj <= rr) sm[rr * 65 + jj] -= sm[rr * 65 + c] * sm[jj * 65 + c];
    }
    __syncthreads();
  }
#pragma unroll
  for (int l = 0; l < 16; ++l) {
    int t = tid + l * 256;
    int r = t >> 6, cc = t & 63;
    Ldst[(size_t)r * ld + cc] = (r == cc) ? diag[r] : sm[r * 65 + cc];
  }
  __syncthreads();
  if (tid < 64) invd[tid] = 1.0 / diag[tid];
  __syncthreads();
  if (tid < 64) {            // thread c solves column c of inv(L) into upper of sm
    int c = tid;
    for (int r = c + 1; r < 64; ++r) {
      double s = sm[r * 65 + c] * invd[c];
      for (int j = c + 1; j < r; ++j) s += sm[r * 65 + j] * sm[c * 65 + j];
      sm[c * 65 + r] = -s * invd[r];
    }
  }
  __syncthreads();
#pragma unroll
  for (int l = 0; l < 16; ++l) {
    int t = tid + l * 256;
    int r = t >> 6, c = t & 63;
    iLout[t] = (r < c) ? 0.0 : (r == c ? invd[r] : sm[c * 65 + r]);
  }
  for (int idx = tid; idx < 4096; idx += 256) {   // W = iL^T iL
    int r = idx >> 6, c = idx & 63;
    int k2 = r > c ? r : c;
    double s = 0.0;
    for (; k2 < 64; ++k2) {
      double ar = (k2 == r) ? invd[r] : sm[r * 65 + k2];
      double ac = (k2 == c) ? invd[c] : sm[c * 65 + k2];
      s += ar * ac;
    }
    Wout[idx] = s;
  }
}

// fused panel step: block t < nbp*(nbp+1)/2 handles trailing tile (i,j);
// j==0 blocks also emit the L21 panel tile; block 0 then factors next diagonal.
#define PFS1(r, c) sm[(r) * 65 + (c)]
#define PFS2(r, c) sm[4288 + (r) * 33 + (c)]
__device__ __forceinline__ void chol_panel(double* sm, double* M, int ld, int k, int nbp,
                                           const double* iLcur, const double* Wcur,
                                           double* LGm, double* iLnext, double* Wnext) {
  int tid = threadIdx.x;
  int t = blockIdx.x;
  int tiles = nbp * (nbp + 1) / 2;
  if (t >= tiles) return;
  int i = 0;
  while ((i + 1) * (i + 2) / 2 <= t) ++i;
  int j = t - i * (i + 1) / 2;
  int tr4 = (tid >> 4) * 4, tc4 = (tid & 15) * 4;
  int rowAi = k + 64 + i * 64, rowAj = k + 64 + j * 64;

  // Phase A (j==0): Li = Ai * iL^T  -> LG panel
  if (j == 0) {
#pragma unroll
    for (int l = 0; l < 16; ++l) { int t2 = tid + l * 256; PFS1(t2 >> 6, t2 & 63) = iLcur[t2]; }
    __syncthreads();
    double li[4][4] = {};
    for (int k0 = 0; k0 < 64; k0 += 32) {
#pragma unroll
      for (int l = 0; l < 8; ++l) {
        int t2 = tid + l * 256;
        PFS2(t2 >> 5, t2 & 31) = M[(size_t)(rowAi + (t2 >> 5)) * ld + k + k0 + (t2 & 31)];
      }
      __syncthreads();
#pragma unroll
      for (int mm = 0; mm < 32; ++mm) {
        double a[4], b[4];
#pragma unroll
        for (int i2 = 0; i2 < 4; ++i2) a[i2] = PFS2(tr4 + i2, mm);
#pragma unroll
        for (int j2 = 0; j2 < 4; ++j2) b[j2] = PFS1(tc4 + j2, k0 + mm);
#pragma unroll
        for (int i2 = 0; i2 < 4; ++i2)
#pragma unroll
          for (int j2 = 0; j2 < 4; ++j2) li[i2][j2] += a[i2] * b[j2];
      }
      __syncthreads();
    }
#pragma unroll
    for (int i2 = 0; i2 < 4; ++i2)
#pragma unroll
      for (int j2 = 0; j2 < 4; ++j2)
        LGm[(size_t)(rowAi + tr4 + i2) * ld + k + tc4 + j2] = li[i2][j2];
  }
  __syncthreads();

  // Phase B: tile (i,j) -= Ai * W * Aj^T
#pragma unroll
  for (int l = 0; l < 16; ++l) { int t2 = tid + l * 256; PFS1(t2 >> 6, t2 & 63) = Wcur[t2]; }
  __syncthreads();
  double acc[4][4] = {};
  for (int k0 = 0; k0 < 64; k0 += 32) {   // D1 = W * Aj^T
#pragma unroll
    for (int l = 0; l < 8; ++l) {
      int t2 = tid + l * 256;
      PFS2(t2 >> 5, t2 & 31) = M[(size_t)(rowAj + (t2 >> 5)) * ld + k + k0 + (t2 & 31)];
    }
    __syncthreads();
#pragma unroll
    for (int mm = 0; mm < 32; ++mm) {
      double a[4], b[4];
#pragma unroll
      for (int i2 = 0; i2 < 4; ++i2) a[i2] = PFS1(tr4 + i2, k0 + mm);
#pragma unroll
      for (int j2 = 0; j2 < 4; ++j2) b[j2] = PFS2(tc4 + j2, mm);
#pragma unroll
      for (int i2 = 0; i2 < 4; ++i2)
#pragma unroll
        for (int j2 = 0; j2 < 4; ++j2) acc[i2][j2] += a[i2] * b[j2];
    }
    __syncthreads();
  }
#pragma unroll
  for (int i2 = 0; i2 < 4; ++i2)   // stash D1 over dead W
#pragma unroll
    for (int j2 = 0; j2 < 4; ++j2) PFS1(tr4 + i2, tc4 + j2) = acc[i2][j2];
  __syncthreads();
  double acc2[4][4] = {};
  for (int k0 = 0; k0 < 64; k0 += 32) {   // C2 = Ai * D1
#pragma unroll
    for (int l = 0; l < 8; ++l) {
      int t2 = tid + l * 256;
      PFS2(t2 >> 5, t2 & 31) = M[(size_t)(rowAi + (t2 >> 5)) * ld + k + k0 + (t2 & 31)];
    }
    __syncthreads();
#pragma unroll
    for (int mm = 0; mm < 32; ++mm) {
      double a[4], b[4];
#pragma unroll
      for (int i2 = 0; i2 < 4; ++i2) a[i2] = PFS2(tr4 + i2, mm);
#pragma unroll
      for (int j2 = 0; j2 < 4; ++j2) b[j2] = PFS1(k0 + mm, tc4 + j2);
#pragma unroll
      for (int i2 = 0; i2 < 4; ++i2)
#pragma unroll
        for (int j2 = 0; j2 < 4; ++j2) acc2[i2][j2] += a[i2] * b[j2];
    }
    __syncthreads();
  }
  double upd[4][4];
#pragma unroll
  for (int i2 = 0; i2 < 4; ++i2)
#pragma unroll
    for (int j2 = 0; j2 < 4; ++j2) {
      size_t off = (size_t)(rowAi + tr4 + i2) * ld + rowAj + tc4 + j2;
      upd[i2][j2] = M[off] - acc2[i2][j2];
      M[off] = upd[i2][j2];
    }

  // Phase C (block 0 == tile (0,0) == next diagonal)
  if (t == 0) {
    __syncthreads();
#pragma unroll
    for (int i2 = 0; i2 < 4; ++i2)
#pragma unroll
      for (int j2 = 0; j2 < 4; ++j2) PFS1(tr4 + i2, tc4 + j2) = upd[i2][j2];
    __syncthreads();
    potrf_inv_w(sm, tid, LGm + (size_t)(k + 64) * ld + (k + 64), ld, iLnext, Wnext);
  }
}

// generic fp64 GEMM cores on the shared pool (64x64 C tile, 4x4 micro)
__device__ __forceinline__ void dgemm_nn_core(double* sm, const double* A, int lda,
                                              const double* B, int ldb,
                                              double* C, int ldc,
                                              int kBeg, int kEnd, double alpha) {
  double* As = sm;          // 64x33
  double* Bs = sm + 2112;   // 32x65
  int tid = threadIdx.x;
  int tr4 = (tid >> 4) * 4, tc4 = (tid & 15) * 4;
  double acc[4][4] = {};
  for (int k0 = kBeg; k0 < kEnd; k0 += 32) {
#pragma unroll
    for (int l = 0; l < 8; ++l) {
      int t = tid + l * 256;
      As[(t >> 5) * 33 + (t & 31)] = A[(size_t)(t >> 5) * lda + k0 + (t & 31)];
    }
#pragma unroll
    for (int l = 0; l < 8; ++l) {
      int t = tid + l * 256;
      Bs[(t >> 6) * 65 + (t & 63)] = B[(size_t)(k0 + (t >> 6)) * ldb + (t & 63)];
    }
    __syncthreads();
#pragma unroll
    for (int kk = 0; kk < 32; ++kk) {
      double a[4], b[4];
#pragma unroll
      for (int i = 0; i < 4; ++i) a[i] = As[(tr4 + i) * 33 + kk];
#pragma unroll
      for (int jx = 0; jx < 4; ++jx) b[jx] = Bs[kk * 65 + tc4 + jx];
#pragma unroll
      for (int i = 0; i < 4; ++i)
#pragma unroll
        for (int jx = 0; jx < 4; ++jx) acc[i][jx] += a[i] * b[jx];
    }
    __syncthreads();
  }
#pragma unroll
  for (int i = 0; i < 4; ++i)
#pragma unroll
    for (int jx = 0; jx < 4; ++jx)
      C[(size_t)(tr4 + i) * ldc + tc4 + jx] = alpha * acc[i][jx];
}

__device__ __forceinline__ void dgemm_tn_core(double* sm, const double* A, int lda,
                                              const double* B, int ldb,
                                              double* C, int ldc,
                                              int kBeg, int kEnd, double alpha) {
  double* Ls = sm;          // 32x65
  double* Bs = sm + 2080;   // 32x65
  int tid = threadIdx.x;
  int tr4 = (tid >> 4) * 4, tc4 = (tid & 15) * 4;
  double acc[4][4] = {};
  for (int k0 = kBeg; k0 < kEnd; k0 += 32) {
#pragma unroll
    for (int l = 0; l < 8; ++l) {
      int t = tid + l * 256;
      Ls[(t >> 6) * 65 + (t & 63)] = A[(size_t)(k0 + (t >> 6)) * lda + (t & 63)];
    }
#pragma unroll
    for (int l = 0; l < 8; ++l) {
      int t = tid + l * 256;
      Bs[(t >> 6) * 65 + (t & 63)] = B[(size_t)(k0 + (t >> 6)) * ldb + (t & 63)];
    }
    __syncthreads();
#pragma unroll
    for (int kk = 0; kk < 32; ++kk) {
      double a[4], b[4];
#pragma unroll
      for (int i = 0; i < 4; ++i) a[i] = Ls[kk * 65 + tr4 + i];
#pragma unroll
      for (int jx = 0; jx < 4; ++jx) b[jx] = Bs[kk * 65 + tc4 + jx];
#pragma unroll
      for (int i = 0; i < 4; ++i)
#pragma unroll
        for (int jx = 0; jx < 4; ++jx) acc[i][jx] += a[i] * b[jx];
    }
    __syncthreads();
  }
#pragma unroll
  for (int i = 0; i < 4; ++i)
#pragma unroll
    for (int jx = 0; jx < 4; ++jx)
      C[(size_t)(tr4 + i) * ldc + tc4 + jx] = alpha * acc[i][jx];
}

__device__ __forceinline__ void buildS_tile(double* sm, const double* GCC,
                                            const double* TA, double* S, int t) {
  double* Ga = sm;          // 64x33
  double* Tb = sm + 2112;   // 32x65
  int tid = threadIdx.x;
  int tr4 = (tid >> 4) * 4, tc4 = (tid & 15) * 4;
  int a0 = (t >> 3) * 64, b0 = (t & 7) * 64;
  double acc[4][4] = {};
  for (int f0 = 0; f0 < NG; f0 += 32) {
#pragma unroll
    for (int l = 0; l < 8; ++l) {
      int t2 = tid + l * 256;
      Ga[(t2 >> 5) * 33 + (t2 & 31)] = GCC[(size_t)(1000 + a0 + (t2 >> 5)) * NCRP + f0 + (t2 & 31)];
    }
#pragma unroll
    for (int l = 0; l < 8; ++l) {
      int t2 = tid + l * 256;
      Tb[(t2 >> 6) * 65 + (t2 & 63)] = TA[(size_t)(f0 + (t2 >> 6)) * NS + b0 + (t2 & 63)];
    }
    __syncthreads();
#pragma unroll
    for (int kk = 0; kk < 32; ++kk) {
      double a[4], b[4];
#pragma unroll
      for (int i = 0; i < 4; ++i) a[i] = Ga[(tr4 + i) * 33 + kk];
#pragma unroll
      for (int jx = 0; jx < 4; ++jx) b[jx] = Tb[kk * 65 + tc4 + jx];
#pragma unroll
      for (int i = 0; i < 4; ++i)
#pragma unroll
        for (int jx = 0; jx < 4; ++jx) acc[i][jx] += a[i] * b[jx];
    }
    __syncthreads();
  }
#pragma unroll
  for (int i = 0; i < 4; ++i)
#pragma unroll
    for (int jx = 0; jx < 4; ++jx) {
      int a = a0 + tr4 + i, b = b0 + tc4 + jx;
      double v;
      if (a < NAR && b < NAR)
        v = (GCC[(size_t)(1000 + a) * NCRP + 1000 + b] - acc[i][jx]) * INVDP;
      else
        v = (a == b) ? 1.0 : 0.0;
      S[(size_t)a * NS + b] = v;
    }
}

__device__ __forceinline__ void gemmM_tile(double* sm, const double* TA, const double* X12,
                                           const float* q, const float* r,
                                           float* Mraw, int t) {
  double* Ga = sm;          // 64x33
  double* Xb = sm + 2112;   // 32x65
  int tid = threadIdx.x;
  int tr4 = (tid >> 4) * 4, tc4 = (tid & 15) * 4;
  int o0 = (t / 18) * 64, c0 = (t % 18) * 64;
  double acc[4][4] = {};
  for (int k0 = 0; k0 < NS; k0 += 32) {
#pragma unroll
    for (int l = 0; l < 8; ++l) {
      int t2 = tid + l * 256;
      Ga[(t2 >> 5) * 33 + (t2 & 31)] = TA[(size_t)(o0 + (t2 >> 5)) * NS + k0 + (t2 & 31)];
    }
#pragma unroll
    for (int l = 0; l < 8; ++l) {
      int t2 = tid + l * 256;
      Xb[(t2 >> 6) * 65 + (t2 & 63)] = X12[(size_t)(k0 + (t2 >> 6)) * NXC + c0 + (t2 & 63)];
    }
    __syncthreads();
#pragma unroll
    for (int kk = 0; kk < 32; ++kk) {
      double a[4], b[4];
#pragma unroll
      for (int i = 0; i < 4; ++i) a[i] = Ga[(tr4 + i) * 33 + kk];
#pragma unroll
      for (int jx = 0; jx < 4; ++jx) b[jx] = Xb[kk * 65 + tc4 + jx];
#pragma unroll
      for (int i = 0; i < 4; ++i)
#pragma unroll
        for (int jx = 0; jx < 4; ++jx) acc[i][jx] += a[i] * b[jx];
    }
    __syncthreads();
  }
#pragma unroll
  for (int i = 0; i < 4; ++i)
#pragma unroll
    for (int jx = 0; jx < 4; ++jx) {
      int o = o0 + tr4 + i, col = c0 + tc4 + jx;
      float v = 0.f;
      if (o < NFR) {
        double scale = 1.0 / (2.0 * dweight(o, q, r));
        double tt = acc[i][jx] * scale;
        v = (float)((col < 600) ? -tt : tt);
      }
      Mraw[(size_t)o * NXC + col] = v;
    }
}

// ==================== the single-chain kernel (software grid barrier) ====================
__global__ __launch_bounds__(256) void k_coop(
    double* GCC, double* G, double* TA, double* S, double* X12,
    float* MRAW, float* MALL,
    double* ILG, double* ILS, double* IDG, double* IDS,
    double* WG, double* WS, double* LG, double* LS,
    double* TB, double* TINV, double* XB,
    const float* qv, const float* rv, unsigned int* bar) {
  __shared__ double sm[6400];  // 51.2 KB pool shared by all stage cores
  const int tid = threadIdx.x;
  const int bid = blockIdx.x;
  const int nbk = gridDim.x;
  const int gsz = nbk * 256;
  const int gix = bid * 256 + tid;
  unsigned int phase = 0;

  // ---- S1: G = GFF + (1e-6/d) I (identity-padded); TA = F A^T (zero-padded) ----
  for (int idx = gix; idx < NG * NG; idx += gsz) {
    int i = idx >> 10, j = idx & 1023;
    double v = (i < NFR && j < NFR) ? GCC[(size_t)i * NCRP + j] : 0.0;
    if (i == j) v = (i < NFR) ? v + 1e-6 / dweight(i, qv, rv) : 1.0;
    G[idx] = v;
  }
  for (int idx = gix; idx < NG * NS; idx += gsz) {
    int f = idx >> 9, a = idx & 511;
    TA[idx] = (f < NFR && a < NAR) ? GCC[(size_t)f * NCRP + 1000 + a] : 0.0;
  }
  gbar(bar, &phase);

  // ---- S2: Cholesky of G (16 panels); last panel also inits ILG (diag<15 + zeros) ----
  if (bid == 0) {
    for (int l = 0; l < 16; ++l) {
      int t2 = tid + l * 256;
      sm[(t2 >> 6) * 65 + (t2 & 63)] = G[(size_t)(t2 >> 6) * NG + (t2 & 63)];
    }
    __syncthreads();
    potrf_inv_w(sm, tid, LG, NG, IDG, WG);
  }
  gbar(bar, &phase);
  for (int p = 0; p < 15; ++p) {
    chol_panel(sm, G, NG, p * 64, 15 - p, IDG + (size_t)p * 4096, WG + (size_t)p * 4096,
               LG, IDG + (size_t)(p + 1) * 4096, WG + (size_t)(p + 1) * 4096);
    if (p == 14 && bid > 0) {  // fold iL_G init into the final (1-tile) panel phase
      for (int idx = (bid - 1) * 256 + tid; idx < NG * NG; idx += (nbk - 1) * 256) {
        int i = idx >> 10, j = idx & 1023, d = i >> 6;
        if (d == 15 && (j >> 6) == 15) continue;  // IDG[15] being written now; copied in S3 lvl0
        ILG[idx] = ((j >> 6) == d) ? IDG[(size_t)d * 4096 + (i & 63) * 64 + (j & 63)] : 0.0;
      }
    }
    gbar(bar, &phase);
  }

  // ---- S3: iL_G via D&C (log depth) ----
  for (int lv = 0; lv < 4; ++lv) {
    int half = 64 << lv, pairs = NG / (2 * half), hb = half >> 6;
    int tiles = pairs * hb * hb;
    if (lv == 0 && bid == 200) {  // late diag-15 copy; readers (fin) run after the bar
      for (int idx = tid; idx < 4096; idx += 256)
        ILG[(size_t)(960 + (idx >> 6)) * NG + 960 + (idx & 63)] = IDG[(size_t)15 * 4096 + idx];
    }
    for (int t = bid; t < tiles; t += nbk) {
      int p = t / (hb * hb), rem = t % (hb * hb), bi = rem / hb, bj = rem % hb;
      int base = p * 2 * half;
      dgemm_nn_core(sm, LG + (size_t)(base + half + bi * 64) * NG + base, NG,
                    ILG + (size_t)base * NG + base + bj * 64, NG,
                    TINV + (size_t)p * half * half + (size_t)bi * 64 * half + bj * 64, half,
                    0, half, 1.0);
    }
    gbar(bar, &phase);
    for (int t = bid; t < tiles; t += nbk) {
      int p = t / (hb * hb), rem = t % (hb * hb), bi = rem / hb, bj = rem % hb;
      int base = p * 2 * half;
      dgemm_nn_core(sm, ILG + (size_t)(base + half + bi * 64) * NG + base + half, NG,
                    TINV + (size_t)p * half * half + bj * 64, half,
                    ILG + (size_t)(base + half + bi * 64) * NG + base + bj * 64, NG,
                    0, half, -1.0);
    }
    gbar(bar, &phase);
  }

  // ---- S4: TA <- iL^T (iL TA)  (triangle-aware K ranges) ----
  for (int t = bid; t < 128; t += nbk) {
    int bi = t >> 3, bj = t & 7;
    dgemm_nn_core(sm, ILG + (size_t)bi * 64 * NG, NG, TA + bj * 64, NS,
                  TB + (size_t)bi * 64 * NS + bj * 64, NS, 0, (bi + 1) * 64, 1.0);
  }
  gbar(bar, &phase);
  for (int t = bid; t < 128; t += nbk) {
    int bi = t >> 3, bj = t & 7;
    dgemm_tn_core(sm, ILG + bi * 64, NG, TB + bj * 64, NS,
                  TA + (size_t)bi * 64 * NS + bj * 64, NS, bi * 64, NG, 1.0);
  }
  gbar(bar, &phase);

  // ---- S5: S = (GAA - GAF*TA)/(2*DELTA)  +  X12 rhs fill (needs only TA) ----
  for (int t = bid; t < 64; t += nbk) buildS_tile(sm, GCC, TA, S, t);
  for (int a = bid; a < NS; a += nbk)
    for (int c = tid; c < NXC; c += 256) {
      double v = 0.0;
      if (a < NAR) {
        if (c < 600) v = TA[(size_t)(400 + c) * NS + a];
        else if (c < 1106) v = (a == (c - 600)) ? 1.0 : 0.0;
      }
      X12[(size_t)a * NXC + c] = v;
    }
  gbar(bar, &phase);

  // ---- S6: Cholesky of S (8 panels); last panel inits ILS (diag<7 + zeros) ----
  if (bid == 0) {
    for (int l = 0; l < 16; ++l) {
      int t2 = tid + l * 256;
      sm[(t2 >> 6) * 65 + (t2 & 63)] = S[(size_t)(t2 >> 6) * NS + (t2 & 63)];
    }
    __syncthreads();
    potrf_inv_w(sm, tid, LS, NS, IDS, WS);
  }
  gbar(bar, &phase);
  for (int p = 0; p < 7; ++p) {
    chol_panel(sm, S, NS, p * 64, 7 - p, IDS + (size_t)p * 4096, WS + (size_t)p * 4096,
               LS, IDS + (size_t)(p + 1) * 4096, WS + (size_t)(p + 1) * 4096);
    if (p == 6 && bid > 0) {
      for (int idx = (bid - 1) * 256 + tid; idx < NS * NS; idx += (nbk - 1) * 256) {
        int i = idx >> 9, j = idx & 511, d = i >> 6;
        if (d == 7 && (j >> 6) == 7) continue;  // IDS[7] copied in S7 lvl0
        ILS[idx] = ((j >> 6) == d) ? IDS[(size_t)d * 4096 + (i & 63) * 64 + (j & 63)] : 0.0;
      }
    }
    gbar(bar, &phase);
  }

  // ---- S7: iL_S via D&C ----
  for (int lv = 0; lv < 3; ++lv) {
    int half = 64 << lv, pairs = NS / (2 * half), hb = half >> 6;
    int tiles = pairs * hb * hb;
    if (lv == 0 && bid == 200) {  // late diag-7 copy
      for (int idx = tid; idx < 4096; idx += 256)
        ILS[(size_t)(448 + (idx >> 6)) * NS + 448 + (idx & 63)] = IDS[(size_t)7 * 4096 + idx];
    }
    for (int t = bid; t < tiles; t += nbk) {
      int p = t / (hb * hb), rem = t % (hb * hb), bi = rem / hb, bj = rem % hb;
      int base = p * 2 * half;
      dgemm_nn_core(sm, LS + (size_t)(base + half + bi * 64) * NS + base, NS,
                    ILS + (size_t)base * NS + base + bj * 64, NS,
                    TINV + (size_t)p * half * half + (size_t)bi * 64 * half + bj * 64, half,
                    0, half, 1.0);
    }
    gbar(bar, &phase);
    for (int t = bid; t < tiles; t += nbk) {
      int p = t / (hb * hb), rem = t % (hb * hb), bi = rem / hb, bj = rem % hb;
      int base = p * 2 * half;
      dgemm_nn_core(sm, ILS + (size_t)(base + half + bi * 64) * NS + base + half, NS,
                    TINV + (size_t)p * half * half + bj * 64, half,
                    ILS + (size_t)(base + half + bi * 64) * NS + base + bj * 64, NS,
                    0, half, -1.0);
    }
    gbar(bar, &phase);
  }

  // ---- S8: X12 = S^{-1} X12  (2 GEMMs) ----
  for (int t = bid; t < 8 * 18; t += nbk) {
    int bi = t / 18, bj = t % 18;
    dgemm_nn_core(sm, ILS + (size_t)bi * 64 * NS, NS, X12 + bj * 64, NXC,
                  XB + (size_t)bi * 64 * NXC + bj * 64, NXC, 0, (bi + 1) * 64, 1.0);
  }
  gbar(bar, &phase);
  for (int t = bid; t < 8 * 18; t += nbk) {
    int bi = t / 18, bj = t % 18;
    dgemm_tn_core(sm, ILS + bi * 64, NS, XB + bj * 64, NXC,
                  X12 + (size_t)bi * 64 * NXC + bj * 64, NXC, bi * 64, NS, 1.0);
  }
  gbar(bar, &phase);

  // ---- S9: Mraw ----
  for (int t = bid; t < 16 * 18; t += nbk) gemmM_tile(sm, TA, X12, qv, rv, MRAW, t);
  gbar(bar, &phase);

  // ---- S10: assemble fp32 map ----
  for (int o = bid; o < NG; o += nbk)
    for (int j2 = tid; j2 < LDMA; j2 += 256) {
      float v = 0.f;
      if (j2 < 600) {
        v = MRAW[(size_t)o * NXC + j2];
        if (o == 400 + j2) v += 1.0f;
        if (j2 >= 594) v += MRAW[(size_t)o * NXC + 1100 + (j2 - 594)];
      } else if (j2 < 1100) {
        v = MRAW[(size_t)o * NXC + j2];
      }
      MALL[(size_t)o * LDMA + j2] = v;
    }
}

// ==================== launch ====================
extern "C" void kernel_launch(void* const* d_in, const int* in_sizes, int n_in,
                              void* d_out, int out_size, void* d_ws, size_t ws_size,
                              hipStream_t stream) {
  const float* ud  = (const float*)d_in[0];
  const float* yd  = (const float*)d_in[1];
  const float* qv  = (const float*)d_in[2];
  const float* rv  = (const float*)d_in[3];
  const float* ref = (const float*)d_in[4];
  const float* ui  = (const float*)d_in[5];
  const float* yi  = (const float*)d_in[6];
  float* out = (float*)d_out;
  char* w = (char*)d_ws;

  float*  C    = (float*)(w + OFF_C);
  double* GCC  = (double*)(w + OFF_GCC);
  double* G    = (double*)(w + OFF_G);
  double* TA   = (double*)(w + OFF_TA);
  double* S    = (double*)(w + OFF_S);
  double* X12  = (double*)(w + OFF_X12);
  float*  MRAW = (float*)(w + OFF_MRAW);
  float*  MALL = (float*)(w + OFF_MALL);
  float*  INA  = (float*)(w + OFF_INALL);
  double* ILG  = (double*)(w + OFF_ILG);
  double* ILS  = (double*)(w + OFF_ILS);
  double* IDG  = (double*)(w + OFF_IDG);
  double* IDS  = (double*)(w + OFF_IDS);
  double* WG   = (double*)(w + OFF_WG);
  double* WS   = (double*)(w + OFF_WS);
  double* LG   = (double*)(w + OFF_LG);
  double* LS   = (double*)(w + OFF_LS);
  double* TB   = (double*)(w + OFF_TB);
  double* TINV = (double*)(w + OFF_TINV);
  double* XB   = (double*)(w + OFF_XB);
  unsigned int* BAR = (unsigned int*)(w + OFF_BAR);

  k_build_C<<<dim3(8, NCRP), 256, 0, stream>>>(ud, yd, C);
  k_gram<<<dim3(24, 24), 256, 0, stream>>>(C, GCC);
  hipMemsetAsync(BAR, 0, 16384, stream);  // zero arrive[] + release (C-region hole)

  k_coop<<<dim3(NBLK), dim3(256), 0, stream>>>(
      GCC, G, TA, S, X12, MRAW, MALL, ILG, ILS, IDG, IDS,
      WG, WS, LG, LS, TB, TINV, XB, qv, rv, BAR);

  k_transpose_in<<<dim3(NBATCH / 32, LDMA / 32), 256, 0, stream>>>(ref, ui, yi, INA);
  k_gemm_out<<<dim3(NBATCH / 128, NG / 128), 256, 0, stream>>>(MALL, INA, out);
}